// Round 5
// baseline (327.317 us; speedup 1.0000x reference)
//
#include <hip/hip_runtime.h>
#include <math.h>

#define Bn 16
#define Nn 1024
#define Dn 128

typedef unsigned short ushort;
typedef unsigned long long u64;
typedef short short8 __attribute__((ext_vector_type(8)));
typedef float f32x4 __attribute__((ext_vector_type(4)));
typedef ushort us8 __attribute__((ext_vector_type(8)));
typedef ushort us4 __attribute__((ext_vector_type(4)));

__device__ __forceinline__ ushort f2bf(float f) {
    unsigned u = __float_as_uint(f);
    u += 0x7fff + ((u >> 16) & 1);           // RTN-even
    return (ushort)(u >> 16);
}
__device__ __forceinline__ float bf2f(ushort s) {
    return __uint_as_float(((unsigned)s) << 16);
}

// ---------------- K0: split weights (Ww->hi/lo, A^T->hi/lo) + Z init ----------------
__global__ __launch_bounds__(256) void k_wprep(const float* __restrict__ Ww,
                                               const float* __restrict__ A,
                                               ushort* __restrict__ Whi,
                                               ushort* __restrict__ Wlo,
                                               ushort* __restrict__ AThi,
                                               ushort* __restrict__ ATlo,
                                               float* __restrict__ Z) {
    int i = blockIdx.x * 256 + threadIdx.x;   // 0..16383
    float w = Ww[i];
    ushort wh = f2bf(w);
    Whi[i] = wh;
    Wlo[i] = f2bf(w - bf2f(wh));
    int e = i >> 7, d = i & 127;
    float a = A[d * Dn + e];
    ushort ah = f2bf(a);
    AThi[i] = ah;
    ATlo[i] = f2bf(a - bf2f(ah));
    Z[i] = (float)Nn;                         // non-edge exp(0) mass, m=0 shift
}

// ---------------- K0b: bit-pack adj: 64 MB f32 -> 2 MB u64 masks ----------------
// thread -> one u64 word = 64 consecutive cols of one row; wave reads 16 KB contiguous
__global__ __launch_bounds__(256) void k_pack(const float* __restrict__ adj,
                                              u64* __restrict__ bm) {
    int widx = blockIdx.x * 256 + threadIdx.x;     // 0..262143
    const float* p = adj + (size_t)widx * 64;
    u64 m = 0;
    #pragma unroll
    for (int k = 0; k < 16; ++k) {
        float4 v = *(const float4*)(p + k * 4);
        u64 bits = (u64)(v.x > 0.f)
                 | ((u64)(v.y > 0.f) << 1)
                 | ((u64)(v.z > 0.f) << 2)
                 | ((u64)(v.w > 0.f) << 3);
        m |= bits << (k * 4);
    }
    bm[widx] = m;
}

// ---------------- K1: fused MFMA: h = x @ Ww^T + b ; hA = h @ A (hi/lo split) ----------------
__global__ __launch_bounds__(256) void k_h(const float* __restrict__ x,
                                           const float* __restrict__ Wb,
                                           const ushort* __restrict__ Whi,
                                           const ushort* __restrict__ Wlo,
                                           const ushort* __restrict__ AThi,
                                           const ushort* __restrict__ ATlo,
                                           float* __restrict__ h,
                                           ushort* __restrict__ h16,
                                           ushort* __restrict__ hA16) {
    int I0 = blockIdx.x * 16;
    int t = threadIdx.x, w = t >> 6, lane = t & 63;
    int m = lane & 15, q = lane >> 4;

    __shared__ float hs[16][Dn + 4];

    const float* px = x + (size_t)(I0 + m) * Dn;
    f32x4 acc0 = {0,0,0,0}, acc1 = {0,0,0,0};
    #pragma unroll
    for (int ks = 0; ks < 4; ++ks) {
        int k0 = q * 8 + ks * 32;
        float v[8]; short8 ahi, alo;
        *(float4*)(v)     = *(const float4*)(px + k0);
        *(float4*)(v + 4) = *(const float4*)(px + k0 + 4);
        #pragma unroll
        for (int j = 0; j < 8; ++j) {
            ushort hi = f2bf(v[j]);
            ahi[j] = (short)hi;
            alo[j] = (short)f2bf(v[j] - bf2f(hi));
        }
        #pragma unroll
        for (int nn = 0; nn < 2; ++nn) {
            int brow = (w * 2 + nn) * 16 + m;
            short8 bhi = __builtin_bit_cast(short8, ((const us8*)(Whi + (size_t)brow * Dn))[q + ks * 4]);
            short8 blo = __builtin_bit_cast(short8, ((const us8*)(Wlo + (size_t)brow * Dn))[q + ks * 4]);
            f32x4 acc = nn ? acc1 : acc0;
            acc = __builtin_amdgcn_mfma_f32_16x16x32_bf16(ahi, bhi, acc, 0, 0, 0);
            acc = __builtin_amdgcn_mfma_f32_16x16x32_bf16(alo, bhi, acc, 0, 0, 0);
            acc = __builtin_amdgcn_mfma_f32_16x16x32_bf16(ahi, blo, acc, 0, 0, 0);
            if (nn) acc1 = acc; else acc0 = acc;
        }
    }
    #pragma unroll
    for (int nn = 0; nn < 2; ++nn) {
        int col = (w * 2 + nn) * 16 + m;
        float bias = Wb[col];
        f32x4 acc = nn ? acc1 : acc0;
        #pragma unroll
        for (int r = 0; r < 4; ++r) {
            int rl = q * 4 + r;
            float hv = acc[r] + bias;
            size_t o = (size_t)(I0 + rl) * Dn + col;
            h[o] = hv;
            h16[o] = f2bf(hv);
            hs[rl][col] = hv;
        }
    }
    __syncthreads();

    f32x4 bcc0 = {0,0,0,0}, bcc1 = {0,0,0,0};
    #pragma unroll
    for (int ks = 0; ks < 4; ++ks) {
        int k0 = q * 8 + ks * 32;
        float v[8]; short8 ahi, alo;
        *(float4*)(v)     = *(const float4*)(&hs[m][k0]);
        *(float4*)(v + 4) = *(const float4*)(&hs[m][k0 + 4]);
        #pragma unroll
        for (int j = 0; j < 8; ++j) {
            ushort hi = f2bf(v[j]);
            ahi[j] = (short)hi;
            alo[j] = (short)f2bf(v[j] - bf2f(hi));
        }
        #pragma unroll
        for (int nn = 0; nn < 2; ++nn) {
            int brow = (w * 2 + nn) * 16 + m;
            short8 bhi = __builtin_bit_cast(short8, ((const us8*)(AThi + (size_t)brow * Dn))[q + ks * 4]);
            short8 blo = __builtin_bit_cast(short8, ((const us8*)(ATlo + (size_t)brow * Dn))[q + ks * 4]);
            f32x4 acc = nn ? bcc1 : bcc0;
            acc = __builtin_amdgcn_mfma_f32_16x16x32_bf16(ahi, bhi, acc, 0, 0, 0);
            acc = __builtin_amdgcn_mfma_f32_16x16x32_bf16(alo, bhi, acc, 0, 0, 0);
            acc = __builtin_amdgcn_mfma_f32_16x16x32_bf16(ahi, blo, acc, 0, 0, 0);
            if (nn) bcc1 = acc; else bcc0 = acc;
        }
    }
    #pragma unroll
    for (int nn = 0; nn < 2; ++nn) {
        int col = (w * 2 + nn) * 16 + m;
        f32x4 acc = nn ? bcc1 : bcc0;
        #pragma unroll
        for (int r = 0; r < 4; ++r) {
            int rl = q * 4 + r;
            hA16[(size_t)(I0 + rl) * Dn + col] = f2bf(acc[r]);
        }
    }
}

// ---------------- K3: scores: MFMA -> LDS -> mask(bits)/exp/coalesced-store + colsum ----------------
__global__ __launch_bounds__(256) void k_scores(const ushort* __restrict__ h16,
                                                const ushort* __restrict__ hA16,
                                                const u64* __restrict__ bm,
                                                ushort* __restrict__ E,
                                                float* __restrict__ Z) {
    int b  = blockIdx.z;
    int I0 = blockIdx.x * 64;
    int J0 = blockIdx.y * 64;
    int t = threadIdx.x, wid = t >> 6, lane = t & 63;
    int m = lane & 15, q = lane >> 4;

    __shared__ float sc[64][68];
    __shared__ float cz[4][64];

    const size_t hb = (size_t)b * Nn * Dn;
    int rowA = I0 + wid * 16 + m;
    const us8* pA1 = (const us8*)(hA16 + hb + (size_t)rowA * Dn);
    const us8* pA2 = (const us8*)(h16  + hb + (size_t)rowA * Dn);
    const us8* pBh[4]; const us8* pBa[4];
    #pragma unroll
    for (int nt = 0; nt < 4; ++nt) {
        int rb = J0 + nt * 16 + m;
        pBh[nt] = (const us8*)(h16  + hb + (size_t)rb * Dn);
        pBa[nt] = (const us8*)(hA16 + hb + (size_t)rb * Dn);
    }

    f32x4 acc[4] = {};
    #pragma unroll
    for (int ks = 0; ks < 4; ++ks) {
        int idx = q + ks * 4;
        short8 a1 = __builtin_bit_cast(short8, pA1[idx]);
        short8 a2 = __builtin_bit_cast(short8, pA2[idx]);
        #pragma unroll
        for (int nt = 0; nt < 4; ++nt) {
            short8 b1 = __builtin_bit_cast(short8, pBh[nt][idx]);
            short8 b2 = __builtin_bit_cast(short8, pBa[nt][idx]);
            acc[nt] = __builtin_amdgcn_mfma_f32_16x16x32_bf16(a1, b1, acc[nt], 0, 0, 0);
            acc[nt] = __builtin_amdgcn_mfma_f32_16x16x32_bf16(a2, b2, acc[nt], 0, 0, 0);
        }
    }
    #pragma unroll
    for (int nt = 0; nt < 4; ++nt)
        #pragma unroll
        for (int r = 0; r < 4; ++r)
            sc[wid * 16 + q * 4 + r][nt * 16 + m] = acc[nt][r];
    __syncthreads();

    // streaming pass: bitmask instead of 64 MB adj
    int row16 = t >> 4, c = t & 15;
    float colsum[4] = {0.f, 0.f, 0.f, 0.f};
    const u64* bmrow = bm + (size_t)(b * Nn + I0) * (Nn / 64) + (J0 >> 6);
    #pragma unroll
    for (int it = 0; it < 4; ++it) {
        int row = it * 16 + row16;
        u64 mw = bmrow[(size_t)row * (Nn / 64)];
        float s4[4];
        *(float4*)s4 = *(const float4*)(&sc[row][c * 4]);
        us4 e4;
        #pragma unroll
        for (int j = 0; j < 4; ++j) {
            float ex = __expf(s4[j]);
            bool on = (mw >> (c * 4 + j)) & 1;
            e4[j] = f2bf(on ? ex : 0.f);
            colsum[j] += on ? (ex - 1.0f) : 0.f;
        }
        *(us4*)(E + ((size_t)b * Nn + I0 + row) * Nn + J0 + c * 4) = e4;
    }
    #pragma unroll
    for (int j = 0; j < 4; ++j) {
        colsum[j] += __shfl_xor(colsum[j], 16, 64);
        colsum[j] += __shfl_xor(colsum[j], 32, 64);
    }
    if (lane < 16) {
        #pragma unroll
        for (int j = 0; j < 4; ++j) cz[wid][lane * 4 + j] = colsum[j];
    }
    __syncthreads();
    if (t < 64) {
        float s = cz[0][t] + cz[1][t] + cz[2][t] + cz[3][t];
        atomicAdd(&Z[b * Nn + J0 + t], s);
    }
}

// ---------------- K4: T[k][j] = src[j][k] / Z[j]  (bf16, transposed) ----------------
__global__ __launch_bounds__(256) void k_prep(const float* __restrict__ src,
                                              const float* __restrict__ Z,
                                              ushort* __restrict__ T) {
    int b = blockIdx.y;
    int j0 = blockIdx.x * 64;
    int t = threadIdx.x;
    __shared__ float ls[64][129];
    __shared__ float iz[64];
    if (t < 64) iz[t] = 1.0f / Z[b * Nn + j0 + t];
    __syncthreads();
    #pragma unroll
    for (int it = 0; it < 32; ++it) {
        int idx = it * 256 + t;
        int j = idx >> 7, k = idx & 127;
        ls[j][k] = src[((size_t)b * Nn + j0 + j) * Dn + k] * iz[j];
    }
    __syncthreads();
    #pragma unroll
    for (int it = 0; it < 32; ++it) {
        int idx = it * 256 + t;
        int k = idx >> 6, j = idx & 63;
        T[((size_t)b * Dn + k) * Nn + j0 + j] = f2bf(ls[j][k]);
    }
}

// ---------------- K5: hop: az = E @ T^T (waves split K), fused relu+gate+lerp;
//                  writes next T (bf16) or final out (f32) ----------------
__global__ __launch_bounds__(256) void k_hop(const ushort* __restrict__ E,
                                             const ushort* __restrict__ T,
                                             const float* __restrict__ h,
                                             const float* __restrict__ Z,
                                             const float* __restrict__ gw,
                                             const float* __restrict__ gb,
                                             ushort* __restrict__ Tnext,
                                             float* __restrict__ out,
                                             int last) {
    int b  = blockIdx.y;
    int I0 = blockIdx.x * 16;
    int t = threadIdx.x, w = t >> 6, lane = t & 63;
    int m = lane & 15, q = lane >> 4;

    __shared__ float red[4][16][136];
    __shared__ ushort tt[128 * 16];

    const us8* pA = (const us8*)(E + ((size_t)b * Nn + I0 + m) * Nn);
    const us8* pB[8];
    #pragma unroll
    for (int nt = 0; nt < 8; ++nt)
        pB[nt] = (const us8*)(T + ((size_t)b * Dn + nt * 16 + m) * Nn);

    f32x4 acc[8] = {};
    #pragma unroll
    for (int ks = 0; ks < 8; ++ks) {
        int idx = w * 32 + ks * 4 + q;
        short8 a = __builtin_bit_cast(short8, pA[idx]);
        #pragma unroll
        for (int nt = 0; nt < 8; ++nt)
            acc[nt] = __builtin_amdgcn_mfma_f32_16x16x32_bf16(
                a, __builtin_bit_cast(short8, pB[nt][idx]), acc[nt], 0, 0, 0);
    }
    #pragma unroll
    for (int nt = 0; nt < 8; ++nt)
        #pragma unroll
        for (int r = 0; r < 4; ++r)
            red[w][q * 4 + r][nt * 16 + m] = acc[nt][r];
    __syncthreads();

    int row = t >> 4, c = t & 15;
    float gb0 = gb[0];
    float azv[8], hv[8];
    float gsum = 0.f;
    size_t hbase = ((size_t)b * Nn + I0 + row) * Dn;
    #pragma unroll
    for (int j = 0; j < 8; ++j) {
        int k = c + 16 * j;
        float v = red[0][row][k] + red[1][row][k] + red[2][row][k] + red[3][row][k];
        v = fmaxf(v, 0.f);
        float hh = h[hbase + k];
        azv[j] = v; hv[j] = hh;
        gsum += hh * gw[k] + v * gw[Dn + k];
    }
    gsum += __shfl_xor(gsum, 1, 64);
    gsum += __shfl_xor(gsum, 2, 64);
    gsum += __shfl_xor(gsum, 4, 64);
    gsum += __shfl_xor(gsum, 8, 64);
    float coef = 1.0f / (1.0f + __expf(-(gsum + gb0)));

    if (last) {
        #pragma unroll
        for (int j = 0; j < 8; ++j)
            out[hbase + c + 16 * j] = coef * hv[j] + (1.f - coef) * azv[j];
    } else {
        float iz = 1.0f / Z[b * Nn + I0 + row];
        #pragma unroll
        for (int j = 0; j < 8; ++j) {
            int k = c + 16 * j;
            tt[k * 16 + row] = f2bf((coef * hv[j] + (1.f - coef) * azv[j]) * iz);
        }
        __syncthreads();
        int k2 = t >> 1, r0 = (t & 1) * 8;
        *(us8*)(Tnext + ((size_t)b * Dn + k2) * Nn + I0 + r0) = *(const us8*)(&tt[k2 * 16 + r0]);
    }
}

extern "C" void kernel_launch(void* const* d_in, const int* in_sizes, int n_in,
                              void* d_out, int out_size, void* d_ws, size_t ws_size,
                              hipStream_t stream) {
    const float* x    = (const float*)d_in[0];   // [B,N,128]
    const float* adj  = (const float*)d_in[1];   // [B,N,N]
    const float* Ww   = (const float*)d_in[2];   // [128,128]
    const float* Wb   = (const float*)d_in[3];   // [128]
    const float* A    = (const float*)d_in[4];   // [128,128]
    const float* gw   = (const float*)d_in[5];   // [1,256]
    const float* gb   = (const float*)d_in[6];   // [1]
    float* out = (float*)d_out;                  // [B,N,128] f32

    char* ws = (char*)d_ws;
    float*  h    = (float*)(ws);                          // 8 MB f32
    ushort* h16  = (ushort*)(ws + (8u << 20));            // 4 MB bf16 (dead after k_scores)
    ushort* hA16 = (ushort*)(ws + (12u << 20));           // 4 MB bf16 (dead after k_scores)
    ushort* Ta   = (ushort*)(ws + (8u << 20));            // aliases h16
    ushort* Tb   = (ushort*)(ws + (12u << 20));           // aliases hA16
    ushort* E    = (ushort*)(ws + (16u << 20));           // 32 MB bf16
    float*  Z    = (float*)(ws + (48u << 20));            // 64 KB
    ushort* Whi  = (ushort*)(ws + (48u << 20) + (64u << 10));
    ushort* Wlo  = (ushort*)(ws + (48u << 20) + (96u << 10));
    ushort* AThi = (ushort*)(ws + (48u << 20) + (128u << 10));
    ushort* ATlo = (ushort*)(ws + (48u << 20) + (160u << 10));
    u64*    bm   = (u64*)(ws + (48u << 20) + (192u << 10));  // 2 MB bitmask
    // total ~50.2 MB

    k_wprep <<<64, 256, 0, stream>>>(Ww, A, Whi, Wlo, AThi, ATlo, Z);
    k_pack  <<<1024, 256, 0, stream>>>(adj, bm);
    k_h     <<<1024, 256, 0, stream>>>(x, Wb, Whi, Wlo, AThi, ATlo, h, h16, hA16);
    k_scores<<<dim3(16, 16, Bn), 256, 0, stream>>>(h16, hA16, bm, E, Z);
    k_prep  <<<dim3(16, Bn), 256, 0, stream>>>(h, Z, Ta);          // T0 = h/Z
    k_hop   <<<dim3(64, Bn), 256, 0, stream>>>(E, Ta, h, Z, gw, gb, Tb, out, 0);
    k_hop   <<<dim3(64, Bn), 256, 0, stream>>>(E, Tb, h, Z, gw, gb, Ta, out, 0);
    k_hop   <<<dim3(64, Bn), 256, 0, stream>>>(E, Ta, h, Z, gw, gb, (ushort*)nullptr, out, 1);
}

// Round 6
// 273.970 us; speedup vs baseline: 1.1947x; 1.1947x over previous
//
#include <hip/hip_runtime.h>
#include <math.h>

#define Bn 16
#define Nn 1024
#define Dn 128

typedef unsigned short ushort;
typedef unsigned long long u64;
typedef short short8 __attribute__((ext_vector_type(8)));
typedef float f32x4 __attribute__((ext_vector_type(4)));
typedef ushort us8 __attribute__((ext_vector_type(8)));
typedef ushort us4 __attribute__((ext_vector_type(4)));

__device__ __forceinline__ ushort f2bf(float f) {
    unsigned u = __float_as_uint(f);
    u += 0x7fff + ((u >> 16) & 1);           // RTN-even
    return (ushort)(u >> 16);
}
__device__ __forceinline__ float bf2f(ushort s) {
    return __uint_as_float(((unsigned)s) << 16);
}

// ---------------- K0: split weights (Ww->hi/lo, A^T->hi/lo) + Z init ----------------
__global__ __launch_bounds__(256) void k_wprep(const float* __restrict__ Ww,
                                               const float* __restrict__ A,
                                               ushort* __restrict__ Whi,
                                               ushort* __restrict__ Wlo,
                                               ushort* __restrict__ AThi,
                                               ushort* __restrict__ ATlo,
                                               float* __restrict__ Z) {
    int i = blockIdx.x * 256 + threadIdx.x;   // 0..16383
    float w = Ww[i];
    ushort wh = f2bf(w);
    Whi[i] = wh;
    Wlo[i] = f2bf(w - bf2f(wh));
    int e = i >> 7, d = i & 127;
    float a = A[d * Dn + e];
    ushort ah = f2bf(a);
    AThi[i] = ah;
    ATlo[i] = f2bf(a - bf2f(ah));
    Z[i] = (float)Nn;                         // non-edge exp(0) mass, m=0 shift
}

// ---------------- K0b: bit-pack adj: 64 MB f32 -> 2 MB u64 masks ----------------
__global__ __launch_bounds__(256) void k_pack(const float* __restrict__ adj,
                                              u64* __restrict__ bm) {
    int widx = blockIdx.x * 256 + threadIdx.x;     // 0..262143
    const float* p = adj + (size_t)widx * 64;
    u64 m = 0;
    #pragma unroll
    for (int k = 0; k < 16; ++k) {
        float4 v = *(const float4*)(p + k * 4);
        u64 bits = (u64)(v.x > 0.f)
                 | ((u64)(v.y > 0.f) << 1)
                 | ((u64)(v.z > 0.f) << 2)
                 | ((u64)(v.w > 0.f) << 3);
        m |= bits << (k * 4);
    }
    bm[widx] = m;
}

// ---------------- K1: fused MFMA: h = x @ Ww^T + b ; hA = h @ A (hi/lo split) ----------------
__global__ __launch_bounds__(256) void k_h(const float* __restrict__ x,
                                           const float* __restrict__ Wb,
                                           const ushort* __restrict__ Whi,
                                           const ushort* __restrict__ Wlo,
                                           const ushort* __restrict__ AThi,
                                           const ushort* __restrict__ ATlo,
                                           float* __restrict__ h,
                                           ushort* __restrict__ h16,
                                           ushort* __restrict__ hA16) {
    int I0 = blockIdx.x * 16;
    int t = threadIdx.x, w = t >> 6, lane = t & 63;
    int m = lane & 15, q = lane >> 4;

    __shared__ float hs[16][Dn + 4];

    const float* px = x + (size_t)(I0 + m) * Dn;
    f32x4 acc0 = {0,0,0,0}, acc1 = {0,0,0,0};
    #pragma unroll
    for (int ks = 0; ks < 4; ++ks) {
        int k0 = q * 8 + ks * 32;
        float v[8]; short8 ahi, alo;
        *(float4*)(v)     = *(const float4*)(px + k0);
        *(float4*)(v + 4) = *(const float4*)(px + k0 + 4);
        #pragma unroll
        for (int j = 0; j < 8; ++j) {
            ushort hi = f2bf(v[j]);
            ahi[j] = (short)hi;
            alo[j] = (short)f2bf(v[j] - bf2f(hi));
        }
        #pragma unroll
        for (int nn = 0; nn < 2; ++nn) {
            int brow = (w * 2 + nn) * 16 + m;
            short8 bhi = __builtin_bit_cast(short8, ((const us8*)(Whi + (size_t)brow * Dn))[q + ks * 4]);
            short8 blo = __builtin_bit_cast(short8, ((const us8*)(Wlo + (size_t)brow * Dn))[q + ks * 4]);
            f32x4 acc = nn ? acc1 : acc0;
            acc = __builtin_amdgcn_mfma_f32_16x16x32_bf16(ahi, bhi, acc, 0, 0, 0);
            acc = __builtin_amdgcn_mfma_f32_16x16x32_bf16(alo, bhi, acc, 0, 0, 0);
            acc = __builtin_amdgcn_mfma_f32_16x16x32_bf16(ahi, blo, acc, 0, 0, 0);
            if (nn) acc1 = acc; else acc0 = acc;
        }
    }
    #pragma unroll
    for (int nn = 0; nn < 2; ++nn) {
        int col = (w * 2 + nn) * 16 + m;
        float bias = Wb[col];
        f32x4 acc = nn ? acc1 : acc0;
        #pragma unroll
        for (int r = 0; r < 4; ++r) {
            int rl = q * 4 + r;
            float hv = acc[r] + bias;
            size_t o = (size_t)(I0 + rl) * Dn + col;
            h[o] = hv;
            h16[o] = f2bf(hv);
            hs[rl][col] = hv;
        }
    }
    __syncthreads();

    f32x4 bcc0 = {0,0,0,0}, bcc1 = {0,0,0,0};
    #pragma unroll
    for (int ks = 0; ks < 4; ++ks) {
        int k0 = q * 8 + ks * 32;
        float v[8]; short8 ahi, alo;
        *(float4*)(v)     = *(const float4*)(&hs[m][k0]);
        *(float4*)(v + 4) = *(const float4*)(&hs[m][k0 + 4]);
        #pragma unroll
        for (int j = 0; j < 8; ++j) {
            ushort hi = f2bf(v[j]);
            ahi[j] = (short)hi;
            alo[j] = (short)f2bf(v[j] - bf2f(hi));
        }
        #pragma unroll
        for (int nn = 0; nn < 2; ++nn) {
            int brow = (w * 2 + nn) * 16 + m;
            short8 bhi = __builtin_bit_cast(short8, ((const us8*)(AThi + (size_t)brow * Dn))[q + ks * 4]);
            short8 blo = __builtin_bit_cast(short8, ((const us8*)(ATlo + (size_t)brow * Dn))[q + ks * 4]);
            f32x4 acc = nn ? bcc1 : bcc0;
            acc = __builtin_amdgcn_mfma_f32_16x16x32_bf16(ahi, bhi, acc, 0, 0, 0);
            acc = __builtin_amdgcn_mfma_f32_16x16x32_bf16(alo, bhi, acc, 0, 0, 0);
            acc = __builtin_amdgcn_mfma_f32_16x16x32_bf16(ahi, blo, acc, 0, 0, 0);
            if (nn) bcc1 = acc; else bcc0 = acc;
        }
    }
    #pragma unroll
    for (int nn = 0; nn < 2; ++nn) {
        int col = (w * 2 + nn) * 16 + m;
        f32x4 acc = nn ? bcc1 : bcc0;
        #pragma unroll
        for (int r = 0; r < 4; ++r) {
            int rl = q * 4 + r;
            hA16[(size_t)(I0 + rl) * Dn + col] = f2bf(acc[r]);
        }
    }
}

// ---------------- K3: scores: LDS-staged B, register-preloaded A fragments,
//                  MFMA -> LDS -> mask(bits)/exp/coalesced-store + colsum ----------------
__global__ __launch_bounds__(256, 4) void k_scores(const ushort* __restrict__ h16,
                                                   const ushort* __restrict__ hA16,
                                                   const u64* __restrict__ bm,
                                                   ushort* __restrict__ E,
                                                   float* __restrict__ Z) {
    int L = blockIdx.x;
    int b    = ((L & 7) << 1) | (L >> 11);        // XCD-grouped batches
    int tile = (L >> 3) & 255;
    int I0 = (tile >> 4) << 6;
    int J0 = (tile & 15) << 6;
    int t = threadIdx.x, wid = t >> 6, lane = t & 63;
    int m = lane & 15, q = lane >> 4;

    __shared__ __align__(16) char smem[34816 + 1024];
    ushort (*Bh)[136] = (ushort(*)[136])smem;             // h16 J-rows, 272B stride
    ushort (*Ba)[136] = (ushort(*)[136])(smem + 17408);   // hA16 J-rows
    float  (*sc)[68]  = (float(*)[68])smem;               // aliases Bh (dead after MFMA)
    float  (*cz)[64]  = (float(*)[64])(smem + 34816);

    const size_t hb = (size_t)b * Nn * Dn;

    // register-preload A fragments (8 independent 16B gathers)
    int rowA = I0 + wid * 16 + m;
    const us8* pA1 = (const us8*)(hA16 + hb + (size_t)rowA * Dn);
    const us8* pA2 = (const us8*)(h16  + hb + (size_t)rowA * Dn);
    us8 A1[4], A2[4];
    #pragma unroll
    for (int ks = 0; ks < 4; ++ks) { A1[ks] = pA1[q + ks * 4]; A2[ks] = pA2[q + ks * 4]; }

    // cooperative coalesced stage of B rows (64 x 256B x 2 arrays)
    {
        int r16 = t >> 4, c16 = t & 15;
        #pragma unroll
        for (int it = 0; it < 4; ++it) {
            int row = it * 16 + r16;
            size_t g = hb + (size_t)(J0 + row) * Dn + c16 * 8;
            *(us8*)&Bh[row][c16 * 8] = *(const us8*)(h16  + g);
            *(us8*)&Ba[row][c16 * 8] = *(const us8*)(hA16 + g);
        }
    }
    __syncthreads();

    f32x4 acc[4] = {};
    #pragma unroll
    for (int ks = 0; ks < 4; ++ks) {
        short8 a1 = __builtin_bit_cast(short8, A1[ks]);
        short8 a2 = __builtin_bit_cast(short8, A2[ks]);
        int co = (q + ks * 4) * 8;
        #pragma unroll
        for (int nt = 0; nt < 4; ++nt) {
            int row = nt * 16 + m;
            short8 b1 = __builtin_bit_cast(short8, *(const us8*)&Bh[row][co]);
            short8 b2 = __builtin_bit_cast(short8, *(const us8*)&Ba[row][co]);
            acc[nt] = __builtin_amdgcn_mfma_f32_16x16x32_bf16(a1, b1, acc[nt], 0, 0, 0);
            acc[nt] = __builtin_amdgcn_mfma_f32_16x16x32_bf16(a2, b2, acc[nt], 0, 0, 0);
        }
    }
    __syncthreads();                              // staging dead; reuse as sc

    #pragma unroll
    for (int nt = 0; nt < 4; ++nt)
        #pragma unroll
        for (int r = 0; r < 4; ++r)
            sc[wid * 16 + q * 4 + r][nt * 16 + m] = acc[nt][r];
    __syncthreads();

    int row16 = t >> 4, c = t & 15;
    float colsum[4] = {0.f, 0.f, 0.f, 0.f};
    const u64* bmrow = bm + (size_t)(b * Nn + I0) * (Nn / 64) + (J0 >> 6);
    #pragma unroll
    for (int it = 0; it < 4; ++it) {
        int row = it * 16 + row16;
        u64 mw = bmrow[(size_t)row * (Nn / 64)];
        float s4[4];
        *(float4*)s4 = *(const float4*)(&sc[row][c * 4]);
        us4 e4;
        #pragma unroll
        for (int j = 0; j < 4; ++j) {
            float ex = __expf(s4[j]);
            bool on = (mw >> (c * 4 + j)) & 1;
            e4[j] = f2bf(on ? ex : 0.f);
            colsum[j] += on ? (ex - 1.0f) : 0.f;
        }
        *(us4*)(E + ((size_t)b * Nn + I0 + row) * Nn + J0 + c * 4) = e4;
    }
    #pragma unroll
    for (int j = 0; j < 4; ++j) {
        colsum[j] += __shfl_xor(colsum[j], 16, 64);
        colsum[j] += __shfl_xor(colsum[j], 32, 64);
    }
    if (lane < 16) {
        #pragma unroll
        for (int j = 0; j < 4; ++j) cz[wid][lane * 4 + j] = colsum[j];
    }
    __syncthreads();
    if (t < 64) {
        float s = cz[0][t] + cz[1][t] + cz[2][t] + cz[3][t];
        atomicAdd(&Z[b * Nn + J0 + t], s);
    }
}

// ---------------- K4: T[k][j] = src[j][k] / Z[j]  (bf16, transposed) ----------------
__global__ __launch_bounds__(256) void k_prep(const float* __restrict__ src,
                                              const float* __restrict__ Z,
                                              ushort* __restrict__ T) {
    int b = blockIdx.y;
    int j0 = blockIdx.x * 64;
    int t = threadIdx.x;
    __shared__ float ls[64][129];
    __shared__ float iz[64];
    if (t < 64) iz[t] = 1.0f / Z[b * Nn + j0 + t];
    __syncthreads();
    #pragma unroll
    for (int it = 0; it < 32; ++it) {
        int idx = it * 256 + t;
        int j = idx >> 7, k = idx & 127;
        ls[j][k] = src[((size_t)b * Nn + j0 + j) * Dn + k] * iz[j];
    }
    __syncthreads();
    #pragma unroll
    for (int it = 0; it < 32; ++it) {
        int idx = it * 256 + t;
        int k = idx >> 6, j = idx & 63;
        T[((size_t)b * Dn + k) * Nn + j0 + j] = f2bf(ls[j][k]);
    }
}

// ---------------- K5: hop: az = E @ T^T (waves split K), A preloaded,
//                  B double-buffered in registers; fused relu+gate+lerp ----------------
__global__ __launch_bounds__(256, 3) void k_hop(const ushort* __restrict__ E,
                                                const ushort* __restrict__ T,
                                                const float* __restrict__ h,
                                                const float* __restrict__ Z,
                                                const float* __restrict__ gw,
                                                const float* __restrict__ gb,
                                                ushort* __restrict__ Tnext,
                                                float* __restrict__ out,
                                                int last) {
    int L = blockIdx.x;
    int b  = ((L & 7) << 1) | (L >> 9);           // XCD-grouped batches
    int I0 = ((L >> 3) & 63) << 4;
    int t = threadIdx.x, w = t >> 6, lane = t & 63;
    int m = lane & 15, q = lane >> 4;

    __shared__ float red[4][16][136];
    __shared__ ushort tt[128 * 16];

    const us8* pA = (const us8*)(E + ((size_t)b * Nn + I0 + m) * Nn);
    const us8* pB[8];
    #pragma unroll
    for (int nt = 0; nt < 8; ++nt)
        pB[nt] = (const us8*)(T + ((size_t)b * Dn + nt * 16 + m) * Nn);

    // preload all A fragments for this wave's K-quarter (8 x 16B, independent)
    us8 Areg[8];
    #pragma unroll
    for (int ks = 0; ks < 8; ++ks) Areg[ks] = pA[w * 32 + ks * 4 + q];

    // software-pipelined B loads: double buffer, 8 in flight
    us8 B0[8], B1[8];
    #pragma unroll
    for (int nt = 0; nt < 8; ++nt) B0[nt] = pB[nt][w * 32 + q];

    f32x4 acc[8] = {};
    #pragma unroll
    for (int ks = 0; ks < 8; ++ks) {
        us8* cur = (ks & 1) ? B1 : B0;
        us8* nxt = (ks & 1) ? B0 : B1;
        if (ks < 7) {
            int idxn = w * 32 + (ks + 1) * 4 + q;
            #pragma unroll
            for (int nt = 0; nt < 8; ++nt) nxt[nt] = pB[nt][idxn];
        }
        short8 a = __builtin_bit_cast(short8, Areg[ks]);
        #pragma unroll
        for (int nt = 0; nt < 8; ++nt)
            acc[nt] = __builtin_amdgcn_mfma_f32_16x16x32_bf16(
                a, __builtin_bit_cast(short8, cur[nt]), acc[nt], 0, 0, 0);
    }
    #pragma unroll
    for (int nt = 0; nt < 8; ++nt)
        #pragma unroll
        for (int r = 0; r < 4; ++r)
            red[w][q * 4 + r][nt * 16 + m] = acc[nt][r];
    __syncthreads();

    int row = t >> 4, c = t & 15;
    float gb0 = gb[0];
    float azv[8], hv[8];
    float gsum = 0.f;
    size_t hbase = ((size_t)b * Nn + I0 + row) * Dn;
    #pragma unroll
    for (int j = 0; j < 8; ++j) {
        int k = c + 16 * j;
        float v = red[0][row][k] + red[1][row][k] + red[2][row][k] + red[3][row][k];
        v = fmaxf(v, 0.f);
        float hh = h[hbase + k];
        azv[j] = v; hv[j] = hh;
        gsum += hh * gw[k] + v * gw[Dn + k];
    }
    gsum += __shfl_xor(gsum, 1, 64);
    gsum += __shfl_xor(gsum, 2, 64);
    gsum += __shfl_xor(gsum, 4, 64);
    gsum += __shfl_xor(gsum, 8, 64);
    float coef = 1.0f / (1.0f + __expf(-(gsum + gb0)));

    if (last) {
        #pragma unroll
        for (int j = 0; j < 8; ++j)
            out[hbase + c + 16 * j] = coef * hv[j] + (1.f - coef) * azv[j];
    } else {
        float iz = 1.0f / Z[b * Nn + I0 + row];
        #pragma unroll
        for (int j = 0; j < 8; ++j) {
            int k = c + 16 * j;
            tt[k * 16 + row] = f2bf((coef * hv[j] + (1.f - coef) * azv[j]) * iz);
        }
        __syncthreads();
        int k2 = t >> 1, r0 = (t & 1) * 8;
        *(us8*)(Tnext + ((size_t)b * Dn + k2) * Nn + I0 + r0) = *(const us8*)(&tt[k2 * 16 + r0]);
    }
}

extern "C" void kernel_launch(void* const* d_in, const int* in_sizes, int n_in,
                              void* d_out, int out_size, void* d_ws, size_t ws_size,
                              hipStream_t stream) {
    const float* x    = (const float*)d_in[0];   // [B,N,128]
    const float* adj  = (const float*)d_in[1];   // [B,N,N]
    const float* Ww   = (const float*)d_in[2];   // [128,128]
    const float* Wb   = (const float*)d_in[3];   // [128]
    const float* A    = (const float*)d_in[4];   // [128,128]
    const float* gw   = (const float*)d_in[5];   // [1,256]
    const float* gb   = (const float*)d_in[6];   // [1]
    float* out = (float*)d_out;                  // [B,N,128] f32

    char* ws = (char*)d_ws;
    float*  h    = (float*)(ws);                          // 8 MB f32
    ushort* h16  = (ushort*)(ws + (8u << 20));            // 4 MB bf16 (dead after k_scores)
    ushort* hA16 = (ushort*)(ws + (12u << 20));           // 4 MB bf16 (dead after k_scores)
    ushort* Ta   = (ushort*)(ws + (8u << 20));            // aliases h16
    ushort* Tb   = (ushort*)(ws + (12u << 20));           // aliases hA16
    ushort* E    = (ushort*)(ws + (16u << 20));           // 32 MB bf16
    float*  Z    = (float*)(ws + (48u << 20));            // 64 KB
    ushort* Whi  = (ushort*)(ws + (48u << 20) + (64u << 10));
    ushort* Wlo  = (ushort*)(ws + (48u << 20) + (96u << 10));
    ushort* AThi = (ushort*)(ws + (48u << 20) + (128u << 10));
    ushort* ATlo = (ushort*)(ws + (48u << 20) + (160u << 10));
    u64*    bm   = (u64*)(ws + (48u << 20) + (192u << 10));  // 2 MB bitmask
    // total ~50.2 MB

    k_wprep <<<64, 256, 0, stream>>>(Ww, A, Whi, Wlo, AThi, ATlo, Z);
    k_pack  <<<1024, 256, 0, stream>>>(adj, bm);
    k_h     <<<1024, 256, 0, stream>>>(x, Wb, Whi, Wlo, AThi, ATlo, h, h16, hA16);
    k_scores<<<4096, 256, 0, stream>>>(h16, hA16, bm, E, Z);
    k_prep  <<<dim3(16, Bn), 256, 0, stream>>>(h, Z, Ta);          // T0 = h/Z
    k_hop   <<<1024, 256, 0, stream>>>(E, Ta, h, Z, gw, gb, Tb, out, 0);
    k_hop   <<<1024, 256, 0, stream>>>(E, Tb, h, Z, gw, gb, Ta, out, 0);
    k_hop   <<<1024, 256, 0, stream>>>(E, Ta, h, Z, gw, gb, (ushort*)nullptr, out, 1);
}

// Round 7
// 252.540 us; speedup vs baseline: 1.2961x; 1.0849x over previous
//
#include <hip/hip_runtime.h>
#include <math.h>

#define Bn 16
#define Nn 1024
#define Dn 128

typedef unsigned short ushort;
typedef short short8 __attribute__((ext_vector_type(8)));
typedef float f32x4 __attribute__((ext_vector_type(4)));
typedef ushort us8 __attribute__((ext_vector_type(8)));
typedef ushort us4 __attribute__((ext_vector_type(4)));

__device__ __forceinline__ ushort f2bf(float f) {
    unsigned u = __float_as_uint(f);
    u += 0x7fff + ((u >> 16) & 1);           // RTN-even
    return (ushort)(u >> 16);
}
__device__ __forceinline__ float bf2f(ushort s) {
    return __uint_as_float(((unsigned)s) << 16);
}

// ---------------- K0: split weights (Ww->hi/lo, A^T->hi/lo) + Z init ----------------
__global__ __launch_bounds__(256) void k_wprep(const float* __restrict__ Ww,
                                               const float* __restrict__ A,
                                               ushort* __restrict__ Whi,
                                               ushort* __restrict__ Wlo,
                                               ushort* __restrict__ AThi,
                                               ushort* __restrict__ ATlo,
                                               float* __restrict__ Z) {
    int i = blockIdx.x * 256 + threadIdx.x;   // 0..16383
    float w = Ww[i];
    ushort wh = f2bf(w);
    Whi[i] = wh;
    Wlo[i] = f2bf(w - bf2f(wh));
    int e = i >> 7, d = i & 127;
    float a = A[d * Dn + e];
    ushort ah = f2bf(a);
    AThi[i] = ah;
    ATlo[i] = f2bf(a - bf2f(ah));
    Z[i] = (float)Nn;                         // non-edge exp(0) mass, m=0 shift
}

// ---------------- K1: fused MFMA: h = x @ Ww^T + b ; hA = h @ A (hi/lo split) ----------------
__global__ __launch_bounds__(256) void k_h(const float* __restrict__ x,
                                           const float* __restrict__ Wb,
                                           const ushort* __restrict__ Whi,
                                           const ushort* __restrict__ Wlo,
                                           const ushort* __restrict__ AThi,
                                           const ushort* __restrict__ ATlo,
                                           float* __restrict__ h,
                                           ushort* __restrict__ h16,
                                           ushort* __restrict__ hA16) {
    int I0 = blockIdx.x * 16;
    int t = threadIdx.x, w = t >> 6, lane = t & 63;
    int m = lane & 15, q = lane >> 4;

    __shared__ float hs[16][Dn + 4];

    const float* px = x + (size_t)(I0 + m) * Dn;
    f32x4 acc0 = {0,0,0,0}, acc1 = {0,0,0,0};
    #pragma unroll
    for (int ks = 0; ks < 4; ++ks) {
        int k0 = q * 8 + ks * 32;
        float v[8]; short8 ahi, alo;
        *(float4*)(v)     = *(const float4*)(px + k0);
        *(float4*)(v + 4) = *(const float4*)(px + k0 + 4);
        #pragma unroll
        for (int j = 0; j < 8; ++j) {
            ushort hi = f2bf(v[j]);
            ahi[j] = (short)hi;
            alo[j] = (short)f2bf(v[j] - bf2f(hi));
        }
        #pragma unroll
        for (int nn = 0; nn < 2; ++nn) {
            int brow = (w * 2 + nn) * 16 + m;
            short8 bhi = __builtin_bit_cast(short8, ((const us8*)(Whi + (size_t)brow * Dn))[q + ks * 4]);
            short8 blo = __builtin_bit_cast(short8, ((const us8*)(Wlo + (size_t)brow * Dn))[q + ks * 4]);
            f32x4 acc = nn ? acc1 : acc0;
            acc = __builtin_amdgcn_mfma_f32_16x16x32_bf16(ahi, bhi, acc, 0, 0, 0);
            acc = __builtin_amdgcn_mfma_f32_16x16x32_bf16(alo, bhi, acc, 0, 0, 0);
            acc = __builtin_amdgcn_mfma_f32_16x16x32_bf16(ahi, blo, acc, 0, 0, 0);
            if (nn) acc1 = acc; else acc0 = acc;
        }
    }
    #pragma unroll
    for (int nn = 0; nn < 2; ++nn) {
        int col = (w * 2 + nn) * 16 + m;
        float bias = Wb[col];
        f32x4 acc = nn ? acc1 : acc0;
        #pragma unroll
        for (int r = 0; r < 4; ++r) {
            int rl = q * 4 + r;
            float hv = acc[r] + bias;
            size_t o = (size_t)(I0 + rl) * Dn + col;
            h[o] = hv;
            h16[o] = f2bf(hv);
            hs[rl][col] = hv;
        }
    }
    __syncthreads();

    f32x4 bcc0 = {0,0,0,0}, bcc1 = {0,0,0,0};
    #pragma unroll
    for (int ks = 0; ks < 4; ++ks) {
        int k0 = q * 8 + ks * 32;
        float v[8]; short8 ahi, alo;
        *(float4*)(v)     = *(const float4*)(&hs[m][k0]);
        *(float4*)(v + 4) = *(const float4*)(&hs[m][k0 + 4]);
        #pragma unroll
        for (int j = 0; j < 8; ++j) {
            ushort hi = f2bf(v[j]);
            ahi[j] = (short)hi;
            alo[j] = (short)f2bf(v[j] - bf2f(hi));
        }
        #pragma unroll
        for (int nn = 0; nn < 2; ++nn) {
            int brow = (w * 2 + nn) * 16 + m;
            short8 bhi = __builtin_bit_cast(short8, ((const us8*)(AThi + (size_t)brow * Dn))[q + ks * 4]);
            short8 blo = __builtin_bit_cast(short8, ((const us8*)(ATlo + (size_t)brow * Dn))[q + ks * 4]);
            f32x4 acc = nn ? bcc1 : bcc0;
            acc = __builtin_amdgcn_mfma_f32_16x16x32_bf16(ahi, bhi, acc, 0, 0, 0);
            acc = __builtin_amdgcn_mfma_f32_16x16x32_bf16(alo, bhi, acc, 0, 0, 0);
            acc = __builtin_amdgcn_mfma_f32_16x16x32_bf16(ahi, blo, acc, 0, 0, 0);
            if (nn) bcc1 = acc; else bcc0 = acc;
        }
    }
    #pragma unroll
    for (int nn = 0; nn < 2; ++nn) {
        int col = (w * 2 + nn) * 16 + m;
        f32x4 acc = nn ? bcc1 : bcc0;
        #pragma unroll
        for (int r = 0; r < 4; ++r) {
            int rl = q * 4 + r;
            hA16[(size_t)(I0 + rl) * Dn + col] = f2bf(acc[r]);
        }
    }
}

// ---------------- K3: scores: LDS-staged B, reg-preloaded A frags + adj prefetch,
//                  MFMA -> LDS -> mask/exp/coalesced-store + colsum ----------------
__global__ __launch_bounds__(256, 4) void k_scores(const ushort* __restrict__ h16,
                                                   const ushort* __restrict__ hA16,
                                                   const float* __restrict__ adj,
                                                   ushort* __restrict__ E,
                                                   float* __restrict__ Z) {
    int L = blockIdx.x;
    int b    = ((L & 7) << 1) | (L >> 11);        // XCD-grouped batches
    int tile = (L >> 3) & 255;
    int I0 = (tile >> 4) << 6;
    int J0 = (tile & 15) << 6;
    int t = threadIdx.x, wid = t >> 6, lane = t & 63;
    int m = lane & 15, q = lane >> 4;

    __shared__ __align__(16) char smem[34816 + 1024];
    ushort (*Bh)[136] = (ushort(*)[136])smem;             // h16 J-rows, 272B stride
    ushort (*Ba)[136] = (ushort(*)[136])(smem + 17408);   // hA16 J-rows
    float  (*sc)[68]  = (float(*)[68])smem;               // aliases Bh (dead after MFMA)
    float  (*cz)[64]  = (float(*)[64])(smem + 34816);

    const size_t hb = (size_t)b * Nn * Dn;

    // prefetch the adj tile early (used only in the epilogue; exactly-once traffic)
    int row16 = t >> 4, c = t & 15;
    float a4[4][4];
    {
        const float* adjp = adj + ((size_t)b * Nn + I0) * Nn + J0;
        #pragma unroll
        for (int it = 0; it < 4; ++it)
            *(float4*)a4[it] = *(const float4*)(adjp + (size_t)(it * 16 + row16) * Nn + c * 4);
    }

    // register-preload A fragments (8 independent 16B gathers)
    int rowA = I0 + wid * 16 + m;
    const us8* pA1 = (const us8*)(hA16 + hb + (size_t)rowA * Dn);
    const us8* pA2 = (const us8*)(h16  + hb + (size_t)rowA * Dn);
    us8 A1[4], A2[4];
    #pragma unroll
    for (int ks = 0; ks < 4; ++ks) { A1[ks] = pA1[q + ks * 4]; A2[ks] = pA2[q + ks * 4]; }

    // cooperative coalesced stage of B rows (64 x 256B x 2 arrays)
    {
        int r16 = t >> 4, c16 = t & 15;
        #pragma unroll
        for (int it = 0; it < 4; ++it) {
            int row = it * 16 + r16;
            size_t g = hb + (size_t)(J0 + row) * Dn + c16 * 8;
            *(us8*)&Bh[row][c16 * 8] = *(const us8*)(h16  + g);
            *(us8*)&Ba[row][c16 * 8] = *(const us8*)(hA16 + g);
        }
    }
    __syncthreads();

    f32x4 acc[4] = {};
    #pragma unroll
    for (int ks = 0; ks < 4; ++ks) {
        short8 a1 = __builtin_bit_cast(short8, A1[ks]);
        short8 a2 = __builtin_bit_cast(short8, A2[ks]);
        int co = (q + ks * 4) * 8;
        #pragma unroll
        for (int nt = 0; nt < 4; ++nt) {
            int row = nt * 16 + m;
            short8 b1 = __builtin_bit_cast(short8, *(const us8*)&Bh[row][co]);
            short8 b2 = __builtin_bit_cast(short8, *(const us8*)&Ba[row][co]);
            acc[nt] = __builtin_amdgcn_mfma_f32_16x16x32_bf16(a1, b1, acc[nt], 0, 0, 0);
            acc[nt] = __builtin_amdgcn_mfma_f32_16x16x32_bf16(a2, b2, acc[nt], 0, 0, 0);
        }
    }
    __syncthreads();                              // staging dead; reuse as sc

    #pragma unroll
    for (int nt = 0; nt < 4; ++nt)
        #pragma unroll
        for (int r = 0; r < 4; ++r)
            sc[wid * 16 + q * 4 + r][nt * 16 + m] = acc[nt][r];
    __syncthreads();

    float colsum[4] = {0.f, 0.f, 0.f, 0.f};
    #pragma unroll
    for (int it = 0; it < 4; ++it) {
        int row = it * 16 + row16;
        float s4[4];
        *(float4*)s4 = *(const float4*)(&sc[row][c * 4]);
        us4 e4;
        #pragma unroll
        for (int j = 0; j < 4; ++j) {
            float ex = __expf(s4[j]);
            bool on = a4[it][j] > 0.f;
            e4[j] = f2bf(on ? ex : 0.f);
            colsum[j] += on ? (ex - 1.0f) : 0.f;
        }
        *(us4*)(E + ((size_t)b * Nn + I0 + row) * Nn + J0 + c * 4) = e4;
    }
    #pragma unroll
    for (int j = 0; j < 4; ++j) {
        colsum[j] += __shfl_xor(colsum[j], 16, 64);
        colsum[j] += __shfl_xor(colsum[j], 32, 64);
    }
    if (lane < 16) {
        #pragma unroll
        for (int j = 0; j < 4; ++j) cz[wid][lane * 4 + j] = colsum[j];
    }
    __syncthreads();
    if (t < 64) {
        float s = cz[0][t] + cz[1][t] + cz[2][t] + cz[3][t];
        atomicAdd(&Z[b * Nn + J0 + t], s);
    }
}

// ---------------- K4: T[k][j] = src[j][k] / Z[j]  (bf16, transposed) ----------------
__global__ __launch_bounds__(256) void k_prep(const float* __restrict__ src,
                                              const float* __restrict__ Z,
                                              ushort* __restrict__ T) {
    int b = blockIdx.y;
    int j0 = blockIdx.x * 64;
    int t = threadIdx.x;
    __shared__ float ls[64][129];
    __shared__ float iz[64];
    if (t < 64) iz[t] = 1.0f / Z[b * Nn + j0 + t];
    __syncthreads();
    #pragma unroll
    for (int it = 0; it < 32; ++it) {
        int idx = it * 256 + t;
        int j = idx >> 7, k = idx & 127;
        ls[j][k] = src[((size_t)b * Nn + j0 + j) * Dn + k] * iz[j];
    }
    __syncthreads();
    #pragma unroll
    for (int it = 0; it < 32; ++it) {
        int idx = it * 256 + t;
        int k = idx >> 6, j = idx & 63;
        T[((size_t)b * Dn + k) * Nn + j0 + j] = f2bf(ls[j][k]);
    }
}

// ---------------- K5: hop: az = E @ T^T with LDS-staged T chunks (XOR-swizzled),
//                  2 waves x 16 rows, full K per wave; fused relu+gate+lerp ----------------
__global__ __launch_bounds__(128, 2) void k_hop(const ushort* __restrict__ E,
                                                const ushort* __restrict__ T,
                                                const float* __restrict__ h,
                                                const float* __restrict__ Z,
                                                const float* __restrict__ gw,
                                                const float* __restrict__ gb,
                                                ushort* __restrict__ Tnext,
                                                float* __restrict__ out,
                                                int last) {
    int L = blockIdx.x;                           // 512 blocks
    int b = ((L & 7) << 1) | (L >> 8);            // XCD-grouped batches (2/XCD)
    int I0 = ((L >> 3) & 31) << 5;                // 32-row tile
    int t = threadIdx.x, w = t >> 6, lane = t & 63;
    int m = lane & 15, q = lane >> 4;

    __shared__ ushort Ts[128][128];               // 32 KB, XOR-swizzled us8 units
    __shared__ ushort tt[2][128][18];             // transpose buf, padded (9.2 KB)

    int rowA = I0 + w * 16 + m;
    const us8* pA = (const us8*)(E + ((size_t)b * Nn + rowA) * Nn);
    const ushort* Trow = T + ((size_t)b * Dn + t) * Nn;   // thread t owns T row t

    f32x4 acc[8] = {};
    for (int cch = 0; cch < 8; ++cch) {           // K chunks of 128
        // stage T[128][cch*128 .. +128] -> Ts, swizzled: unit u -> u ^ (row&15)
        const ushort* src = Trow + cch * 128;
        #pragma unroll
        for (int u = 0; u < 16; ++u)
            *(us8*)&Ts[t][((u ^ (t & 15)) << 3)] = *(const us8*)(src + u * 8);
        __syncthreads();
        #pragma unroll
        for (int ks = 0; ks < 4; ++ks) {
            short8 a = __builtin_bit_cast(short8, pA[cch * 16 + ks * 4 + q]);
            #pragma unroll
            for (int nt = 0; nt < 8; ++nt) {
                int row = nt * 16 + m;
                int unit = (ks * 4 + q) ^ m;       // read-side swizzle (row&15 == m)
                short8 bf = __builtin_bit_cast(short8, *(const us8*)&Ts[row][unit << 3]);
                acc[nt] = __builtin_amdgcn_mfma_f32_16x16x32_bf16(a, bf, acc[nt], 0, 0, 0);
            }
        }
        __syncthreads();
    }

    // epilogue: relu + gate + lerp (wave-local; wave owns 16 rows x all 128 cols)
    float gb0 = gb[0];
    float azv[8], hv[8];
    float gsum = 0.f;
    #pragma unroll
    for (int nt = 0; nt < 8; ++nt) {
        int k = nt * 16 + m;
        float w1 = gw[k], w2 = gw[Dn + k];
        // each lane carries 4 rows (q*4+r); fold over r separately below
        (void)w1; (void)w2;
        azv[nt] = 0.f; hv[nt] = 0.f;              // placeholders (per-r below)
    }
    // per-r processing: gate sum is per row, so loop rows r
    float coef_r[4];
    float az_s[8][4], hv_s[8][4];
    #pragma unroll
    for (int r = 0; r < 4; ++r) {
        int row = I0 + w * 16 + q * 4 + r;
        size_t hbase = ((size_t)b * Nn + row) * Dn;
        float gs = 0.f;
        #pragma unroll
        for (int nt = 0; nt < 8; ++nt) {
            int k = nt * 16 + m;
            float a = fmaxf(acc[nt][r], 0.f);
            float hh = h[hbase + k];
            az_s[nt][r] = a; hv_s[nt][r] = hh;
            gs += hh * gw[k] + a * gw[Dn + k];
        }
        gs += __shfl_xor(gs, 1, 64);
        gs += __shfl_xor(gs, 2, 64);
        gs += __shfl_xor(gs, 4, 64);
        gs += __shfl_xor(gs, 8, 64);              // sum over the 16 m-lanes
        coef_r[r] = 1.0f / (1.0f + __expf(-(gs + gb0)));
    }

    if (last) {
        #pragma unroll
        for (int r = 0; r < 4; ++r) {
            int row = I0 + w * 16 + q * 4 + r;
            size_t hbase = ((size_t)b * Nn + row) * Dn;
            #pragma unroll
            for (int nt = 0; nt < 8; ++nt)
                out[hbase + nt * 16 + m] = coef_r[r] * hv_s[nt][r] + (1.f - coef_r[r]) * az_s[nt][r];
        }
    } else {
        #pragma unroll
        for (int r = 0; r < 4; ++r) {
            int row = I0 + w * 16 + q * 4 + r;
            float iz = 1.0f / Z[b * Nn + row];
            #pragma unroll
            for (int nt = 0; nt < 8; ++nt) {
                float v = coef_r[r] * hv_s[nt][r] + (1.f - coef_r[r]) * az_s[nt][r];
                tt[w][nt * 16 + m][q * 4 + r] = f2bf(v * iz);
            }
        }
        __syncthreads();
        // cooperative transposed store: thread t -> T-row k=t, both wave tiles
        #pragma unroll
        for (int ww = 0; ww < 2; ++ww) {
            size_t o = ((size_t)b * Dn + t) * Nn + I0 + ww * 16;
            *(us8*)(Tnext + o)     = *(const us8*)&tt[ww][t][0];
            *(us8*)(Tnext + o + 8) = *(const us8*)&tt[ww][t][8];
        }
    }
}

extern "C" void kernel_launch(void* const* d_in, const int* in_sizes, int n_in,
                              void* d_out, int out_size, void* d_ws, size_t ws_size,
                              hipStream_t stream) {
    const float* x    = (const float*)d_in[0];   // [B,N,128]
    const float* adj  = (const float*)d_in[1];   // [B,N,N]
    const float* Ww   = (const float*)d_in[2];   // [128,128]
    const float* Wb   = (const float*)d_in[3];   // [128]
    const float* A    = (const float*)d_in[4];   // [128,128]
    const float* gw   = (const float*)d_in[5];   // [1,256]
    const float* gb   = (const float*)d_in[6];   // [1]
    float* out = (float*)d_out;                  // [B,N,128] f32

    char* ws = (char*)d_ws;
    float*  h    = (float*)(ws);                          // 8 MB f32
    ushort* h16  = (ushort*)(ws + (8u << 20));            // 4 MB bf16 (dead after k_scores)
    ushort* hA16 = (ushort*)(ws + (12u << 20));           // 4 MB bf16 (dead after k_scores)
    ushort* Ta   = (ushort*)(ws + (8u << 20));            // aliases h16
    ushort* Tb   = (ushort*)(ws + (12u << 20));           // aliases hA16
    ushort* E    = (ushort*)(ws + (16u << 20));           // 32 MB bf16
    float*  Z    = (float*)(ws + (48u << 20));            // 64 KB
    ushort* Whi  = (ushort*)(ws + (48u << 20) + (64u << 10));
    ushort* Wlo  = (ushort*)(ws + (48u << 20) + (96u << 10));
    ushort* AThi = (ushort*)(ws + (48u << 20) + (128u << 10));
    ushort* ATlo = (ushort*)(ws + (48u << 20) + (160u << 10));
    // total ~48.2 MB

    k_wprep <<<64, 256, 0, stream>>>(Ww, A, Whi, Wlo, AThi, ATlo, Z);
    k_h     <<<1024, 256, 0, stream>>>(x, Wb, Whi, Wlo, AThi, ATlo, h, h16, hA16);
    k_scores<<<4096, 256, 0, stream>>>(h16, hA16, adj, E, Z);
    k_prep  <<<dim3(16, Bn), 256, 0, stream>>>(h, Z, Ta);          // T0 = h/Z
    k_hop   <<<512, 128, 0, stream>>>(E, Ta, h, Z, gw, gb, Tb, out, 0);
    k_hop   <<<512, 128, 0, stream>>>(E, Tb, h, Z, gw, gb, Ta, out, 0);
    k_hop   <<<512, 128, 0, stream>>>(E, Ta, h, Z, gw, gb, (ushort*)nullptr, out, 1);
}

// Round 8
// 250.028 us; speedup vs baseline: 1.3091x; 1.0100x over previous
//
#include <hip/hip_runtime.h>
#include <math.h>

#define Bn 16
#define Nn 1024
#define Dn 128

typedef unsigned short ushort;
typedef short short8 __attribute__((ext_vector_type(8)));
typedef float f32x4 __attribute__((ext_vector_type(4)));
typedef ushort us8 __attribute__((ext_vector_type(8)));
typedef ushort us4 __attribute__((ext_vector_type(4)));

__device__ __forceinline__ ushort f2bf(float f) {
    unsigned u = __float_as_uint(f);
    u += 0x7fff + ((u >> 16) & 1);           // RTN-even
    return (ushort)(u >> 16);
}
__device__ __forceinline__ float bf2f(ushort s) {
    return __uint_as_float(((unsigned)s) << 16);
}

// Fragment layouts (us8 units of 8 ushorts):
//   Ef: unit = (((b*64 + rt)*32 + kc)*16 + m)*4 + q   -> A[m][kc*32+q*8+e], rows rt*16+m
//   Tf: unit = (((b*8  + nt)*32 + kc)*16 + m)*4 + q   -> B[nt*16+m][kc*32+q*8+e] (d=nt*16+m, K=j)

// ---------------- K0: split weights (Ww->hi/lo, A^T->hi/lo) + Z init ----------------
__global__ __launch_bounds__(256) void k_wprep(const float* __restrict__ Ww,
                                               const float* __restrict__ A,
                                               ushort* __restrict__ Whi,
                                               ushort* __restrict__ Wlo,
                                               ushort* __restrict__ AThi,
                                               ushort* __restrict__ ATlo,
                                               float* __restrict__ Z) {
    int i = blockIdx.x * 256 + threadIdx.x;   // 0..16383
    float w = Ww[i];
    ushort wh = f2bf(w);
    Whi[i] = wh;
    Wlo[i] = f2bf(w - bf2f(wh));
    int e = i >> 7, d = i & 127;
    float a = A[d * Dn + e];
    ushort ah = f2bf(a);
    AThi[i] = ah;
    ATlo[i] = f2bf(a - bf2f(ah));
    Z[i] = (float)Nn;                         // non-edge exp(0) mass, m=0 shift
}

// ---------------- K1: fused MFMA: h = x @ Ww^T + b ; hA = h @ A (hi/lo split) ----------------
__global__ __launch_bounds__(256) void k_h(const float* __restrict__ x,
                                           const float* __restrict__ Wb,
                                           const ushort* __restrict__ Whi,
                                           const ushort* __restrict__ Wlo,
                                           const ushort* __restrict__ AThi,
                                           const ushort* __restrict__ ATlo,
                                           float* __restrict__ h,
                                           ushort* __restrict__ h16,
                                           ushort* __restrict__ hA16) {
    int I0 = blockIdx.x * 16;
    int t = threadIdx.x, w = t >> 6, lane = t & 63;
    int m = lane & 15, q = lane >> 4;

    __shared__ float hs[16][Dn + 4];

    const float* px = x + (size_t)(I0 + m) * Dn;
    f32x4 acc0 = {0,0,0,0}, acc1 = {0,0,0,0};
    #pragma unroll
    for (int ks = 0; ks < 4; ++ks) {
        int k0 = q * 8 + ks * 32;
        float v[8]; short8 ahi, alo;
        *(float4*)(v)     = *(const float4*)(px + k0);
        *(float4*)(v + 4) = *(const float4*)(px + k0 + 4);
        #pragma unroll
        for (int j = 0; j < 8; ++j) {
            ushort hi = f2bf(v[j]);
            ahi[j] = (short)hi;
            alo[j] = (short)f2bf(v[j] - bf2f(hi));
        }
        #pragma unroll
        for (int nn = 0; nn < 2; ++nn) {
            int brow = (w * 2 + nn) * 16 + m;
            short8 bhi = __builtin_bit_cast(short8, ((const us8*)(Whi + (size_t)brow * Dn))[q + ks * 4]);
            short8 blo = __builtin_bit_cast(short8, ((const us8*)(Wlo + (size_t)brow * Dn))[q + ks * 4]);
            f32x4 acc = nn ? acc1 : acc0;
            acc = __builtin_amdgcn_mfma_f32_16x16x32_bf16(ahi, bhi, acc, 0, 0, 0);
            acc = __builtin_amdgcn_mfma_f32_16x16x32_bf16(alo, bhi, acc, 0, 0, 0);
            acc = __builtin_amdgcn_mfma_f32_16x16x32_bf16(ahi, blo, acc, 0, 0, 0);
            if (nn) acc1 = acc; else acc0 = acc;
        }
    }
    #pragma unroll
    for (int nn = 0; nn < 2; ++nn) {
        int col = (w * 2 + nn) * 16 + m;
        float bias = Wb[col];
        f32x4 acc = nn ? acc1 : acc0;
        #pragma unroll
        for (int r = 0; r < 4; ++r) {
            int rl = q * 4 + r;
            float hv = acc[r] + bias;
            size_t o = (size_t)(I0 + rl) * Dn + col;
            h[o] = hv;
            h16[o] = f2bf(hv);
            hs[rl][col] = hv;
        }
    }
    __syncthreads();

    f32x4 bcc0 = {0,0,0,0}, bcc1 = {0,0,0,0};
    #pragma unroll
    for (int ks = 0; ks < 4; ++ks) {
        int k0 = q * 8 + ks * 32;
        float v[8]; short8 ahi, alo;
        *(float4*)(v)     = *(const float4*)(&hs[m][k0]);
        *(float4*)(v + 4) = *(const float4*)(&hs[m][k0 + 4]);
        #pragma unroll
        for (int j = 0; j < 8; ++j) {
            ushort hi = f2bf(v[j]);
            ahi[j] = (short)hi;
            alo[j] = (short)f2bf(v[j] - bf2f(hi));
        }
        #pragma unroll
        for (int nn = 0; nn < 2; ++nn) {
            int brow = (w * 2 + nn) * 16 + m;
            short8 bhi = __builtin_bit_cast(short8, ((const us8*)(AThi + (size_t)brow * Dn))[q + ks * 4]);
            short8 blo = __builtin_bit_cast(short8, ((const us8*)(ATlo + (size_t)brow * Dn))[q + ks * 4]);
            f32x4 acc = nn ? bcc1 : bcc0;
            acc = __builtin_amdgcn_mfma_f32_16x16x32_bf16(ahi, bhi, acc, 0, 0, 0);
            acc = __builtin_amdgcn_mfma_f32_16x16x32_bf16(alo, bhi, acc, 0, 0, 0);
            acc = __builtin_amdgcn_mfma_f32_16x16x32_bf16(ahi, blo, acc, 0, 0, 0);
            if (nn) bcc1 = acc; else bcc0 = acc;
        }
    }
    #pragma unroll
    for (int nn = 0; nn < 2; ++nn) {
        int col = (w * 2 + nn) * 16 + m;
        f32x4 acc = nn ? bcc1 : bcc0;
        #pragma unroll
        for (int r = 0; r < 4; ++r) {
            int rl = q * 4 + r;
            hA16[(size_t)(I0 + rl) * Dn + col] = f2bf(acc[r]);
        }
    }
}

// ---------------- K3: scores: LDS-staged B, reg-preloaded A frags + adj prefetch,
//                  MFMA -> LDS -> mask/exp + colsum; E written in FRAGMENT layout -------
__global__ __launch_bounds__(256, 4) void k_scores(const ushort* __restrict__ h16,
                                                   const ushort* __restrict__ hA16,
                                                   const float* __restrict__ adj,
                                                   ushort* __restrict__ Ef,
                                                   float* __restrict__ Z) {
    int L = blockIdx.x;
    int b    = ((L & 7) << 1) | (L >> 11);        // XCD-grouped batches
    int tile = (L >> 3) & 255;
    int I0 = (tile >> 4) << 6;
    int J0 = (tile & 15) << 6;
    int t = threadIdx.x, wid = t >> 6, lane = t & 63;
    int m = lane & 15, q = lane >> 4;

    __shared__ __align__(16) char smem[34816 + 1024];
    ushort (*Bh)[136] = (ushort(*)[136])smem;             // h16 J-rows, 272B stride
    ushort (*Ba)[136] = (ushort(*)[136])(smem + 17408);   // hA16 J-rows
    float  (*sc)[68]  = (float(*)[68])smem;               // aliases Bh (dead after MFMA)
    float  (*cz)[64]  = (float(*)[64])(smem + 34816);

    const size_t hb = (size_t)b * Nn * Dn;

    // prefetch the adj tile early (used only in the epilogue; exactly-once traffic)
    int row16 = t >> 4, c = t & 15;
    float a4[4][4];
    {
        const float* adjp = adj + ((size_t)b * Nn + I0) * Nn + J0;
        #pragma unroll
        for (int it = 0; it < 4; ++it)
            *(float4*)a4[it] = *(const float4*)(adjp + (size_t)(it * 16 + row16) * Nn + c * 4);
    }

    // register-preload A fragments (8 independent 16B gathers)
    int rowA = I0 + wid * 16 + m;
    const us8* pA1 = (const us8*)(hA16 + hb + (size_t)rowA * Dn);
    const us8* pA2 = (const us8*)(h16  + hb + (size_t)rowA * Dn);
    us8 A1[4], A2[4];
    #pragma unroll
    for (int ks = 0; ks < 4; ++ks) { A1[ks] = pA1[q + ks * 4]; A2[ks] = pA2[q + ks * 4]; }

    // cooperative coalesced stage of B rows (64 x 256B x 2 arrays)
    {
        int r16 = t >> 4, c16 = t & 15;
        #pragma unroll
        for (int it = 0; it < 4; ++it) {
            int row = it * 16 + r16;
            size_t g = hb + (size_t)(J0 + row) * Dn + c16 * 8;
            *(us8*)&Bh[row][c16 * 8] = *(const us8*)(h16  + g);
            *(us8*)&Ba[row][c16 * 8] = *(const us8*)(hA16 + g);
        }
    }
    __syncthreads();

    f32x4 acc[4] = {};
    #pragma unroll
    for (int ks = 0; ks < 4; ++ks) {
        short8 a1 = __builtin_bit_cast(short8, A1[ks]);
        short8 a2 = __builtin_bit_cast(short8, A2[ks]);
        int co = (q + ks * 4) * 8;
        #pragma unroll
        for (int nt = 0; nt < 4; ++nt) {
            int row = nt * 16 + m;
            short8 b1 = __builtin_bit_cast(short8, *(const us8*)&Bh[row][co]);
            short8 b2 = __builtin_bit_cast(short8, *(const us8*)&Ba[row][co]);
            acc[nt] = __builtin_amdgcn_mfma_f32_16x16x32_bf16(a1, b1, acc[nt], 0, 0, 0);
            acc[nt] = __builtin_amdgcn_mfma_f32_16x16x32_bf16(a2, b2, acc[nt], 0, 0, 0);
        }
    }
    __syncthreads();                              // staging dead; reuse as sc

    #pragma unroll
    for (int nt = 0; nt < 4; ++nt)
        #pragma unroll
        for (int r = 0; r < 4; ++r)
            sc[wid * 16 + q * 4 + r][nt * 16 + m] = acc[nt][r];
    __syncthreads();

    float colsum[4] = {0.f, 0.f, 0.f, 0.f};
    #pragma unroll
    for (int it = 0; it < 4; ++it) {
        int row = it * 16 + row16;
        float s4[4];
        *(float4*)s4 = *(const float4*)(&sc[row][c * 4]);
        us4 e4;
        #pragma unroll
        for (int j = 0; j < 4; ++j) {
            float ex = __expf(s4[j]);
            bool on = a4[it][j] > 0.f;
            e4[j] = f2bf(on ? ex : 0.f);
            colsum[j] += on ? (ex - 1.0f) : 0.f;
        }
        // fragment-layout E write: rt = I0/16+it, kc = J0/32 + c/8, m = row16, q=(c&7)>>1, e0=(c&1)*4
        size_t U = ((((size_t)b * 64 + (I0 >> 4) + it) * 32 + (J0 >> 5) + (c >> 3)) * 16 + row16) * 4
                 + ((c & 7) >> 1);
        *(us4*)(Ef + U * 8 + (c & 1) * 4) = e4;
    }
    #pragma unroll
    for (int j = 0; j < 4; ++j) {
        colsum[j] += __shfl_xor(colsum[j], 16, 64);
        colsum[j] += __shfl_xor(colsum[j], 32, 64);
    }
    if (lane < 16) {
        #pragma unroll
        for (int j = 0; j < 4; ++j) cz[wid][lane * 4 + j] = colsum[j];
    }
    __syncthreads();
    if (t < 64) {
        float s = cz[0][t] + cz[1][t] + cz[2][t] + cz[3][t];
        atomicAdd(&Z[b * Nn + J0 + t], s);
    }
}

// ---------------- K4: Tf = fragment-layout (src/Z)^T ----------------
__global__ __launch_bounds__(256) void k_prep(const float* __restrict__ src,
                                              const float* __restrict__ Z,
                                              ushort* __restrict__ Tf) {
    int b = blockIdx.y;
    int j0 = blockIdx.x * 64;
    int t = threadIdx.x;
    __shared__ float ls[64][129];
    __shared__ float iz[64];
    if (t < 64) iz[t] = 1.0f / Z[b * Nn + j0 + t];
    __syncthreads();
    #pragma unroll
    for (int it = 0; it < 32; ++it) {
        int idx = it * 256 + t;
        int j = idx >> 7, k = idx & 127;
        ls[j][k] = src[((size_t)b * Nn + j0 + j) * Dn + k] * iz[j];
    }
    __syncthreads();
    int k = t & 127, half = t >> 7;               // thread: d-row k, 32-j half
    us8 o[4];
    #pragma unroll
    for (int qq = 0; qq < 4; ++qq) {
        us8 tmp;
        #pragma unroll
        for (int e = 0; e < 8; ++e)
            tmp[e] = f2bf(ls[half * 32 + qq * 8 + e][k]);
        o[qq] = tmp;
    }
    size_t U = (((size_t)(k >> 4) * 32 + (j0 >> 5) + half) * 16 + (k & 15)) * 4;
    us8* dst = (us8*)(Tf + (size_t)b * 131072 + U * 8);
    dst[0] = o[0]; dst[1] = o[1]; dst[2] = o[2]; dst[3] = o[3];
}

// ---------------- K5: hop GEMM on fragment layouts: zero-LDS barrier-free K-loop,
//                  16-row tiles, 4 waves split cols; fused relu+gate+lerp ----------------
__global__ __launch_bounds__(256, 4) void k_hop(const ushort* __restrict__ Ef,
                                                const ushort* __restrict__ Tf,
                                                const float* __restrict__ h,
                                                const float* __restrict__ Z,
                                                const float* __restrict__ gw,
                                                const float* __restrict__ gb,
                                                ushort* __restrict__ Tfn,
                                                float* __restrict__ out,
                                                int last) {
    int L = blockIdx.x;                           // 1024 blocks
    int b  = ((L & 7) << 1) | (L >> 9);           // XCD-grouped batches
    int rt = (L >> 3) & 63;                       // 16-row tile
    int I0 = rt << 4;
    int t = threadIdx.x, w = t >> 6, lane = t & 63;
    int m = lane & 15, q = lane >> 4;

    __shared__ float red[4][16];
    __shared__ float cs[16], zz[16];
    __shared__ ushort tt[128][24];                // padded: 16B-aligned us8 halves

    const us8* pA  = (const us8*)Ef + ((size_t)b * 64 + rt) * 2048 + m * 4 + q;
    const us8* pB0 = (const us8*)Tf + ((size_t)b * 8 + 2 * w) * 2048 + m * 4 + q;
    const us8* pB1 = pB0 + 2048;                  // nt = 2w+1

    f32x4 acc0 = {0,0,0,0}, acc1 = {0,0,0,0};
    #pragma unroll 8
    for (int kc = 0; kc < 32; ++kc) {
        int o = kc * 64;
        short8 a  = __builtin_bit_cast(short8, pA[o]);
        short8 b0 = __builtin_bit_cast(short8, pB0[o]);
        short8 b1 = __builtin_bit_cast(short8, pB1[o]);
        acc0 = __builtin_amdgcn_mfma_f32_16x16x32_bf16(a, b0, acc0, 0, 0, 0);
        acc1 = __builtin_amdgcn_mfma_f32_16x16x32_bf16(a, b1, acc1, 0, 0, 0);
    }

    float gb0 = gb[0];
    int k0 = w * 32 + m, k1 = k0 + 16;
    float g0a = gw[k0], g0z = gw[Dn + k0], g1a = gw[k1], g1z = gw[Dn + k1];
    float hv0[4], hv1[4], az0[4], az1[4];
    size_t hbase = ((size_t)b * Nn + I0) * Dn;
    #pragma unroll
    for (int r = 0; r < 4; ++r) {
        int row = q * 4 + r;
        az0[r] = fmaxf(acc0[r], 0.f);
        az1[r] = fmaxf(acc1[r], 0.f);
        hv0[r] = h[hbase + (size_t)row * Dn + k0];
        hv1[r] = h[hbase + (size_t)row * Dn + k1];
        float gs = hv0[r] * g0a + az0[r] * g0z + hv1[r] * g1a + az1[r] * g1z;
        gs += __shfl_xor(gs, 1, 64);
        gs += __shfl_xor(gs, 2, 64);
        gs += __shfl_xor(gs, 4, 64);
        gs += __shfl_xor(gs, 8, 64);              // sum over the 16 m-lanes
        if (m == 0) red[w][row] = gs;
    }
    __syncthreads();
    if (t < 16) {
        float v = red[0][t] + red[1][t] + red[2][t] + red[3][t];
        cs[t] = 1.0f / (1.0f + __expf(-(v + gb0)));
        zz[t] = 1.0f / Z[b * Nn + I0 + t];
    }
    __syncthreads();

    if (last) {
        #pragma unroll
        for (int r = 0; r < 4; ++r) {
            int row = q * 4 + r;
            float cc = cs[row];
            out[hbase + (size_t)row * Dn + k0] = cc * hv0[r] + (1.f - cc) * az0[r];
            out[hbase + (size_t)row * Dn + k1] = cc * hv1[r] + (1.f - cc) * az1[r];
        }
    } else {
        #pragma unroll
        for (int r = 0; r < 4; ++r) {
            int row = q * 4 + r;
            float cc = cs[row], iz = zz[row];
            tt[k0][row] = f2bf((cc * hv0[r] + (1.f - cc) * az0[r]) * iz);
            tt[k1][row] = f2bf((cc * hv1[r] + (1.f - cc) * az1[r]) * iz);
        }
        __syncthreads();
        // fragment-layout Tf write: thread pair (k, part) -> 8 rows each
        int k = t >> 1, part = t & 1;
        size_t U = (((size_t)(k >> 4) * 32 + (I0 >> 5)) * 16 + (k & 15)) * 4
                 + ((I0 & 31) >> 3) + part;
        *(us8*)(Tfn + (size_t)b * 131072 + U * 8) = *(const us8*)&tt[k][part * 8];
    }
}

extern "C" void kernel_launch(void* const* d_in, const int* in_sizes, int n_in,
                              void* d_out, int out_size, void* d_ws, size_t ws_size,
                              hipStream_t stream) {
    const float* x    = (const float*)d_in[0];   // [B,N,128]
    const float* adj  = (const float*)d_in[1];   // [B,N,N]
    const float* Ww   = (const float*)d_in[2];   // [128,128]
    const float* Wb   = (const float*)d_in[3];   // [128]
    const float* A    = (const float*)d_in[4];   // [128,128]
    const float* gw   = (const float*)d_in[5];   // [1,256]
    const float* gb   = (const float*)d_in[6];   // [1]
    float* out = (float*)d_out;                  // [B,N,128] f32

    char* ws = (char*)d_ws;
    float*  h    = (float*)(ws);                          // 8 MB f32
    ushort* h16  = (ushort*)(ws + (8u << 20));            // 4 MB bf16 (dead after k_scores)
    ushort* hA16 = (ushort*)(ws + (12u << 20));           // 4 MB bf16 (dead after k_scores)
    ushort* Ta   = (ushort*)(ws + (8u << 20));            // aliases h16  (Tf buffers)
    ushort* Tb   = (ushort*)(ws + (12u << 20));           // aliases hA16
    ushort* E    = (ushort*)(ws + (16u << 20));           // 32 MB bf16 (fragment layout)
    float*  Z    = (float*)(ws + (48u << 20));            // 64 KB
    ushort* Whi  = (ushort*)(ws + (48u << 20) + (64u << 10));
    ushort* Wlo  = (ushort*)(ws + (48u << 20) + (96u << 10));
    ushort* AThi = (ushort*)(ws + (48u << 20) + (128u << 10));
    ushort* ATlo = (ushort*)(ws + (48u << 20) + (160u << 10));
    // total ~48.2 MB

    k_wprep <<<64, 256, 0, stream>>>(Ww, A, Whi, Wlo, AThi, ATlo, Z);
    k_h     <<<1024, 256, 0, stream>>>(x, Wb, Whi, Wlo, AThi, ATlo, h, h16, hA16);
    k_scores<<<4096, 256, 0, stream>>>(h16, hA16, adj, E, Z);
    k_prep  <<<dim3(16, Bn), 256, 0, stream>>>(h, Z, Ta);          // Tf0 = (h/Z)^T
    k_hop   <<<1024, 256, 0, stream>>>(E, Ta, h, Z, gw, gb, Tb, out, 0);
    k_hop   <<<1024, 256, 0, stream>>>(E, Tb, h, Z, gw, gb, Ta, out, 0);
    k_hop   <<<1024, 256, 0, stream>>>(E, Ta, h, Z, gw, gb, (ushort*)nullptr, out, 1);
}

// Round 9
// 240.213 us; speedup vs baseline: 1.3626x; 1.0409x over previous
//
#include <hip/hip_runtime.h>
#include <math.h>

#define Bn 16
#define Nn 1024
#define Dn 128

typedef unsigned short ushort;
typedef unsigned long long u64;
typedef short short8 __attribute__((ext_vector_type(8)));
typedef float f32x4 __attribute__((ext_vector_type(4)));
typedef ushort us8 __attribute__((ext_vector_type(8)));
typedef ushort us4 __attribute__((ext_vector_type(4)));

__device__ __forceinline__ ushort f2bf(float f) {
    unsigned u = __float_as_uint(f);
    u += 0x7fff + ((u >> 16) & 1);           // RTN-even
    return (ushort)(u >> 16);
}
__device__ __forceinline__ float bf2f(ushort s) {
    return __uint_as_float(((unsigned)s) << 16);
}

// Fragment layouts (us8 units of 8 ushorts):
//   Ef: unit = (((b*64 + rt)*32 + kc)*16 + m)*4 + q   -> A[m][kc*32+q*8+e], rows rt*16+m
//   Tf: unit = (((b*8  + nt)*32 + kc)*16 + m)*4 + q   -> B[nt*16+m][kc*32+q*8+e] (d=nt*16+m, K=j)

// ---------------- K0: split weights (Ww->hi/lo, A^T->hi/lo) + Z init ----------------
__global__ __launch_bounds__(256) void k_wprep(const float* __restrict__ Ww,
                                               const float* __restrict__ A,
                                               ushort* __restrict__ Whi,
                                               ushort* __restrict__ Wlo,
                                               ushort* __restrict__ AThi,
                                               ushort* __restrict__ ATlo,
                                               float* __restrict__ Z) {
    int i = blockIdx.x * 256 + threadIdx.x;   // 0..16383
    float w = Ww[i];
    ushort wh = f2bf(w);
    Whi[i] = wh;
    Wlo[i] = f2bf(w - bf2f(wh));
    int e = i >> 7, d = i & 127;
    float a = A[d * Dn + e];
    ushort ah = f2bf(a);
    AThi[i] = ah;
    ATlo[i] = f2bf(a - bf2f(ah));
    Z[i] = (float)Nn;                         // non-edge exp(0) mass, m=0 shift
}

// ---------------- K1: fused MFMA h/hA + adj bit-pack in the tail ----------------
__global__ __launch_bounds__(256) void k_h(const float* __restrict__ x,
                                           const float* __restrict__ Wb,
                                           const ushort* __restrict__ Whi,
                                           const ushort* __restrict__ Wlo,
                                           const ushort* __restrict__ AThi,
                                           const ushort* __restrict__ ATlo,
                                           const float* __restrict__ adj,
                                           float* __restrict__ h,
                                           ushort* __restrict__ h16,
                                           ushort* __restrict__ hA16,
                                           u64* __restrict__ bm) {
    int I0 = blockIdx.x * 16;
    int t = threadIdx.x, w = t >> 6, lane = t & 63;
    int m = lane & 15, q = lane >> 4;

    __shared__ float hs[16][Dn + 4];

    const float* px = x + (size_t)(I0 + m) * Dn;
    f32x4 acc0 = {0,0,0,0}, acc1 = {0,0,0,0};
    #pragma unroll
    for (int ks = 0; ks < 4; ++ks) {
        int k0 = q * 8 + ks * 32;
        float v[8]; short8 ahi, alo;
        *(float4*)(v)     = *(const float4*)(px + k0);
        *(float4*)(v + 4) = *(const float4*)(px + k0 + 4);
        #pragma unroll
        for (int j = 0; j < 8; ++j) {
            ushort hi = f2bf(v[j]);
            ahi[j] = (short)hi;
            alo[j] = (short)f2bf(v[j] - bf2f(hi));
        }
        #pragma unroll
        for (int nn = 0; nn < 2; ++nn) {
            int brow = (w * 2 + nn) * 16 + m;
            short8 bhi = __builtin_bit_cast(short8, ((const us8*)(Whi + (size_t)brow * Dn))[q + ks * 4]);
            short8 blo = __builtin_bit_cast(short8, ((const us8*)(Wlo + (size_t)brow * Dn))[q + ks * 4]);
            f32x4 acc = nn ? acc1 : acc0;
            acc = __builtin_amdgcn_mfma_f32_16x16x32_bf16(ahi, bhi, acc, 0, 0, 0);
            acc = __builtin_amdgcn_mfma_f32_16x16x32_bf16(alo, bhi, acc, 0, 0, 0);
            acc = __builtin_amdgcn_mfma_f32_16x16x32_bf16(ahi, blo, acc, 0, 0, 0);
            if (nn) acc1 = acc; else acc0 = acc;
        }
    }
    #pragma unroll
    for (int nn = 0; nn < 2; ++nn) {
        int col = (w * 2 + nn) * 16 + m;
        float bias = Wb[col];
        f32x4 acc = nn ? acc1 : acc0;
        #pragma unroll
        for (int r = 0; r < 4; ++r) {
            int rl = q * 4 + r;
            float hv = acc[r] + bias;
            size_t o = (size_t)(I0 + rl) * Dn + col;
            h[o] = hv;
            h16[o] = f2bf(hv);
            hs[rl][col] = hv;
        }
    }
    __syncthreads();

    f32x4 bcc0 = {0,0,0,0}, bcc1 = {0,0,0,0};
    #pragma unroll
    for (int ks = 0; ks < 4; ++ks) {
        int k0 = q * 8 + ks * 32;
        float v[8]; short8 ahi, alo;
        *(float4*)(v)     = *(const float4*)(&hs[m][k0]);
        *(float4*)(v + 4) = *(const float4*)(&hs[m][k0 + 4]);
        #pragma unroll
        for (int j = 0; j < 8; ++j) {
            ushort hi = f2bf(v[j]);
            ahi[j] = (short)hi;
            alo[j] = (short)f2bf(v[j] - bf2f(hi));
        }
        #pragma unroll
        for (int nn = 0; nn < 2; ++nn) {
            int brow = (w * 2 + nn) * 16 + m;
            short8 bhi = __builtin_bit_cast(short8, ((const us8*)(AThi + (size_t)brow * Dn))[q + ks * 4]);
            short8 blo = __builtin_bit_cast(short8, ((const us8*)(ATlo + (size_t)brow * Dn))[q + ks * 4]);
            f32x4 acc = nn ? bcc1 : bcc0;
            acc = __builtin_amdgcn_mfma_f32_16x16x32_bf16(ahi, bhi, acc, 0, 0, 0);
            acc = __builtin_amdgcn_mfma_f32_16x16x32_bf16(alo, bhi, acc, 0, 0, 0);
            acc = __builtin_amdgcn_mfma_f32_16x16x32_bf16(ahi, blo, acc, 0, 0, 0);
            if (nn) bcc1 = acc; else bcc0 = acc;
        }
    }
    #pragma unroll
    for (int nn = 0; nn < 2; ++nn) {
        int col = (w * 2 + nn) * 16 + m;
        f32x4 acc = nn ? bcc1 : bcc0;
        #pragma unroll
        for (int r = 0; r < 4; ++r) {
            int rl = q * 4 + r;
            hA16[(size_t)(I0 + rl) * Dn + col] = f2bf(acc[r]);
        }
    }

    // fused adj bit-pack (overlaps with other waves' MFMA work)
    {
        int widx = blockIdx.x * 256 + t;          // 0..262143
        const float* p = adj + (size_t)widx * 64;
        u64 mb = 0;
        #pragma unroll
        for (int k = 0; k < 16; ++k) {
            float4 v = *(const float4*)(p + k * 4);
            u64 bits = (u64)(v.x > 0.f)
                     | ((u64)(v.y > 0.f) << 1)
                     | ((u64)(v.z > 0.f) << 2)
                     | ((u64)(v.w > 0.f) << 3);
            mb |= bits << (k * 4);
        }
        bm[widx] = mb;
    }
}

// ---------------- K3: scores: LDS-staged B, reg-preloaded A frags, bitmask mask,
//                  MFMA -> LDS -> exp + colsum; E written in FRAGMENT layout -------
__global__ __launch_bounds__(256, 4) void k_scores(const ushort* __restrict__ h16,
                                                   const ushort* __restrict__ hA16,
                                                   const u64* __restrict__ bm,
                                                   ushort* __restrict__ Ef,
                                                   float* __restrict__ Z) {
    int L = blockIdx.x;
    int b    = ((L & 7) << 1) | (L >> 11);        // XCD-grouped batches
    int tile = (L >> 3) & 255;
    int I0 = (tile >> 4) << 6;
    int J0 = (tile & 15) << 6;
    int t = threadIdx.x, wid = t >> 6, lane = t & 63;
    int m = lane & 15, q = lane >> 4;

    __shared__ __align__(16) char smem[34816 + 1024];
    ushort (*Bh)[136] = (ushort(*)[136])smem;             // h16 J-rows, 272B stride
    ushort (*Ba)[136] = (ushort(*)[136])(smem + 17408);   // hA16 J-rows
    float  (*sc)[68]  = (float(*)[68])smem;               // aliases Bh (dead after MFMA)
    float  (*cz)[64]  = (float(*)[64])(smem + 34816);

    const size_t hb = (size_t)b * Nn * Dn;

    // register-preload A fragments (8 independent 16B gathers)
    int rowA = I0 + wid * 16 + m;
    const us8* pA1 = (const us8*)(hA16 + hb + (size_t)rowA * Dn);
    const us8* pA2 = (const us8*)(h16  + hb + (size_t)rowA * Dn);
    us8 A1[4], A2[4];
    #pragma unroll
    for (int ks = 0; ks < 4; ++ks) { A1[ks] = pA1[q + ks * 4]; A2[ks] = pA2[q + ks * 4]; }

    // cooperative coalesced stage of B rows (64 x 256B x 2 arrays)
    {
        int r16 = t >> 4, c16 = t & 15;
        #pragma unroll
        for (int it = 0; it < 4; ++it) {
            int row = it * 16 + r16;
            size_t g = hb + (size_t)(J0 + row) * Dn + c16 * 8;
            *(us8*)&Bh[row][c16 * 8] = *(const us8*)(h16  + g);
            *(us8*)&Ba[row][c16 * 8] = *(const us8*)(hA16 + g);
        }
    }
    __syncthreads();

    f32x4 acc[4] = {};
    #pragma unroll
    for (int ks = 0; ks < 4; ++ks) {
        short8 a1 = __builtin_bit_cast(short8, A1[ks]);
        short8 a2 = __builtin_bit_cast(short8, A2[ks]);
        int co = (q + ks * 4) * 8;
        #pragma unroll
        for (int nt = 0; nt < 4; ++nt) {
            int row = nt * 16 + m;
            short8 b1 = __builtin_bit_cast(short8, *(const us8*)&Bh[row][co]);
            short8 b2 = __builtin_bit_cast(short8, *(const us8*)&Ba[row][co]);
            acc[nt] = __builtin_amdgcn_mfma_f32_16x16x32_bf16(a1, b1, acc[nt], 0, 0, 0);
            acc[nt] = __builtin_amdgcn_mfma_f32_16x16x32_bf16(a2, b2, acc[nt], 0, 0, 0);
        }
    }
    __syncthreads();                              // staging dead; reuse as sc

    #pragma unroll
    for (int nt = 0; nt < 4; ++nt)
        #pragma unroll
        for (int r = 0; r < 4; ++r)
            sc[wid * 16 + q * 4 + r][nt * 16 + m] = acc[nt][r];
    __syncthreads();

    int row16 = t >> 4, c = t & 15;
    float colsum[4] = {0.f, 0.f, 0.f, 0.f};
    const u64* bmrow = bm + (size_t)(b * Nn + I0) * (Nn / 64) + (J0 >> 6);
    #pragma unroll
    for (int it = 0; it < 4; ++it) {
        int row = it * 16 + row16;
        u64 mw = bmrow[(size_t)row * (Nn / 64)];
        float s4[4];
        *(float4*)s4 = *(const float4*)(&sc[row][c * 4]);
        us4 e4;
        #pragma unroll
        for (int j = 0; j < 4; ++j) {
            float ex = __expf(s4[j]);
            bool on = (mw >> (c * 4 + j)) & 1;
            e4[j] = f2bf(on ? ex : 0.f);
            colsum[j] += on ? (ex - 1.0f) : 0.f;
        }
        // fragment-layout E write
        size_t U = ((((size_t)b * 64 + (I0 >> 4) + it) * 32 + (J0 >> 5) + (c >> 3)) * 16 + row16) * 4
                 + ((c & 7) >> 1);
        *(us4*)(Ef + U * 8 + (c & 1) * 4) = e4;
    }
    #pragma unroll
    for (int j = 0; j < 4; ++j) {
        colsum[j] += __shfl_xor(colsum[j], 16, 64);
        colsum[j] += __shfl_xor(colsum[j], 32, 64);
    }
    if (lane < 16) {
        #pragma unroll
        for (int j = 0; j < 4; ++j) cz[wid][lane * 4 + j] = colsum[j];
    }
    __syncthreads();
    if (t < 64) {
        float s = cz[0][t] + cz[1][t] + cz[2][t] + cz[3][t];
        atomicAdd(&Z[b * Nn + J0 + t], s);
    }
}

// ---------------- K4: Tf = fragment-layout (src/Z)^T ----------------
__global__ __launch_bounds__(256) void k_prep(const float* __restrict__ src,
                                              const float* __restrict__ Z,
                                              ushort* __restrict__ Tf) {
    int b = blockIdx.y;
    int j0 = blockIdx.x * 64;
    int t = threadIdx.x;
    __shared__ float ls[64][129];
    __shared__ float iz[64];
    if (t < 64) iz[t] = 1.0f / Z[b * Nn + j0 + t];
    __syncthreads();
    #pragma unroll
    for (int it = 0; it < 32; ++it) {
        int idx = it * 256 + t;
        int j = idx >> 7, k = idx & 127;
        ls[j][k] = src[((size_t)b * Nn + j0 + j) * Dn + k] * iz[j];
    }
    __syncthreads();
    int k = t & 127, half = t >> 7;               // thread: d-row k, 32-j half
    us8 o[4];
    #pragma unroll
    for (int qq = 0; qq < 4; ++qq) {
        us8 tmp;
        #pragma unroll
        for (int e = 0; e < 8; ++e)
            tmp[e] = f2bf(ls[half * 32 + qq * 8 + e][k]);
        o[qq] = tmp;
    }
    size_t U = (((size_t)(k >> 4) * 32 + (j0 >> 5) + half) * 16 + (k & 15)) * 4;
    us8* dst = (us8*)(Tf + (size_t)b * 131072 + U * 8);
    dst[0] = o[0]; dst[1] = o[1]; dst[2] = o[2]; dst[3] = o[3];
}

// ---------------- K5: hop GEMM, 64-row blocks: wave = 16 rows x ALL 128 cols,
//                  A read once, wave-local gate; fused relu+gate+lerp ----------------
__global__ __launch_bounds__(256, 2) void k_hop(const ushort* __restrict__ Ef,
                                                const ushort* __restrict__ Tf,
                                                const float* __restrict__ h,
                                                const float* __restrict__ Z,
                                                const float* __restrict__ gw,
                                                const float* __restrict__ gb,
                                                ushort* __restrict__ Tfn,
                                                float* __restrict__ out,
                                                int last) {
    int L = blockIdx.x;                           // 256 blocks
    int b  = ((L & 7) << 1) | (L >> 7);           // 8 XCDs x 2 batches
    int t4 = (L >> 3) & 15;                       // 64-row tile
    int t = threadIdx.x, w = t >> 6, lane = t & 63;
    int m = lane & 15, q = lane >> 4;
    int rt = t4 * 4 + w;                          // wave's 16-row MFMA tile
    int I0 = rt << 4;

    __shared__ ushort tt[4][128][16];             // 16 KB transpose buf

    const us8* pA = (const us8*)Ef + ((size_t)b * 64 + rt) * 2048 + m * 4 + q;
    const us8* pB = (const us8*)Tf + (size_t)b * 16384 + m * 4 + q;   // + nt*2048

    f32x4 acc[8] = {};
    #pragma unroll 2
    for (int kc = 0; kc < 32; ++kc) {
        int o = kc * 64;
        short8 a = __builtin_bit_cast(short8, pA[o]);
        #pragma unroll
        for (int nt = 0; nt < 8; ++nt)
            acc[nt] = __builtin_amdgcn_mfma_f32_16x16x32_bf16(
                a, __builtin_bit_cast(short8, pB[nt * 2048 + o]), acc[nt], 0, 0, 0);
    }

    float gb0 = gb[0];
    float gwa[8], gwz[8];
    #pragma unroll
    for (int nt = 0; nt < 8; ++nt) { gwa[nt] = gw[nt * 16 + m]; gwz[nt] = gw[Dn + nt * 16 + m]; }

    float hv[8][4], coef[4];
    size_t hbase = ((size_t)b * Nn + I0) * Dn;
    #pragma unroll
    for (int r = 0; r < 4; ++r) {
        int row = q * 4 + r;
        float gs = 0.f;
        #pragma unroll
        for (int nt = 0; nt < 8; ++nt) {
            float az = fmaxf(acc[nt][r], 0.f);
            acc[nt][r] = az;
            float hh = h[hbase + (size_t)row * Dn + nt * 16 + m];
            hv[nt][r] = hh;
            gs += hh * gwa[nt] + az * gwz[nt];
        }
        gs += __shfl_xor(gs, 1, 64);
        gs += __shfl_xor(gs, 2, 64);
        gs += __shfl_xor(gs, 4, 64);
        gs += __shfl_xor(gs, 8, 64);              // sum over the 16 m-lanes
        coef[r] = 1.0f / (1.0f + __expf(-(gs + gb0)));
    }

    if (last) {
        #pragma unroll
        for (int r = 0; r < 4; ++r) {
            int row = q * 4 + r;
            float cc = coef[r];
            #pragma unroll
            for (int nt = 0; nt < 8; ++nt)
                out[hbase + (size_t)row * Dn + nt * 16 + m] =
                    cc * hv[nt][r] + (1.f - cc) * acc[nt][r];
        }
    } else {
        #pragma unroll
        for (int r = 0; r < 4; ++r) {
            int row = q * 4 + r;
            float cc = coef[r];
            float iz = 1.0f / Z[b * Nn + I0 + row];
            #pragma unroll
            for (int nt = 0; nt < 8; ++nt) {
                float v = cc * hv[nt][r] + (1.f - cc) * acc[nt][r];
                tt[w][nt * 16 + m][row] = f2bf(v * iz);
            }
        }
        __syncthreads();
        // fragment-layout Tf write: thread (k, jh) -> 64B contiguous (4 us8 units)
        int k = t >> 1, jh = t & 1;
        size_t U0 = (((size_t)(k >> 4) * 32 + t4 * 2 + jh) * 16 + (k & 15)) * 4;
        ushort* dst = Tfn + (size_t)b * 131072 + U0 * 8;
        #pragma unroll
        for (int qq = 0; qq < 4; ++qq)
            *(us8*)(dst + qq * 8) = *(const us8*)&tt[jh * 2 + (qq >> 1)][k][(qq & 1) * 8];
    }
}

extern "C" void kernel_launch(void* const* d_in, const int* in_sizes, int n_in,
                              void* d_out, int out_size, void* d_ws, size_t ws_size,
                              hipStream_t stream) {
    const float* x    = (const float*)d_in[0];   // [B,N,128]
    const float* adj  = (const float*)d_in[1];   // [B,N,N]
    const float* Ww   = (const float*)d_in[2];   // [128,128]
    const float* Wb   = (const float*)d_in[3];   // [128]
    const float* A    = (const float*)d_in[4];   // [128,128]
    const float* gw   = (const float*)d_in[5];   // [1,256]
    const float* gb   = (const float*)d_in[6];   // [1]
    float* out = (float*)d_out;                  // [B,N,128] f32

    char* ws = (char*)d_ws;
    float*  h    = (float*)(ws);                          // 8 MB f32
    ushort* h16  = (ushort*)(ws + (8u << 20));            // 4 MB bf16 (dead after k_scores)
    ushort* hA16 = (ushort*)(ws + (12u << 20));           // 4 MB bf16 (dead after k_scores)
    ushort* Ta   = (ushort*)(ws + (8u << 20));            // aliases h16  (Tf buffers)
    ushort* Tb   = (ushort*)(ws + (12u << 20));           // aliases hA16
    ushort* E    = (ushort*)(ws + (16u << 20));           // 32 MB bf16 (fragment layout)
    float*  Z    = (float*)(ws + (48u << 20));            // 64 KB
    ushort* Whi  = (ushort*)(ws + (48u << 20) + (64u << 10));
    ushort* Wlo  = (ushort*)(ws + (48u << 20) + (96u << 10));
    ushort* AThi = (ushort*)(ws + (48u << 20) + (128u << 10));
    ushort* ATlo = (ushort*)(ws + (48u << 20) + (160u << 10));
    u64*    bm   = (u64*)(ws + (48u << 20) + (192u << 10));  // 2 MB bitmask
    // total ~50.2 MB

    k_wprep <<<64, 256, 0, stream>>>(Ww, A, Whi, Wlo, AThi, ATlo, Z);
    k_h     <<<1024, 256, 0, stream>>>(x, Wb, Whi, Wlo, AThi, ATlo, adj, h, h16, hA16, bm);
    k_scores<<<4096, 256, 0, stream>>>(h16, hA16, bm, E, Z);
    k_prep  <<<dim3(16, Bn), 256, 0, stream>>>(h, Z, Ta);          // Tf0 = (h/Z)^T
    k_hop   <<<256, 256, 0, stream>>>(E, Ta, h, Z, gw, gb, Tb, out, 0);
    k_hop   <<<256, 256, 0, stream>>>(E, Tb, h, Z, gw, gb, Ta, out, 0);
    k_hop   <<<256, 256, 0, stream>>>(E, Ta, h, Z, gw, gb, (ushort*)nullptr, out, 1);
}